// Round 8
// baseline (877.667 us; speedup 1.0000x reference)
//
#include <hip/hip_runtime.h>
#include <hip/hip_bf16.h>
#include <math.h>

#define D_EMBED 512
#define NUM_HEADS 8
#define HEAD_DIM 64
#define D_FF 2048
#define BATCH 2
#define SEQ 4096
#define M_ROWS (BATCH*SEQ)   // 8192
// 0.125 * log2(e): folds softmax's exp->exp2 conversion into the Q projection
#define QSCALE 0.18033688011112042f

typedef __attribute__((ext_vector_type(8))) short short8;
typedef __attribute__((ext_vector_type(4))) short short4_t;
typedef __attribute__((ext_vector_type(4))) float f32x4;

#if __has_builtin(__builtin_amdgcn_mfma_f32_16x16x16bf16_1k)
#define MFMA_K16(a,b,c) __builtin_amdgcn_mfma_f32_16x16x16bf16_1k(a,b,c,0,0,0)
#elif __has_builtin(__builtin_amdgcn_mfma_f32_16x16x16_bf16)
#define MFMA_K16(a,b,c) __builtin_amdgcn_mfma_f32_16x16x16_bf16(a,b,c,0,0,0)
#else
#define MFMA_K16(a,b,c) (c)   // host-pass parse stub
#endif

#if __has_builtin(__builtin_amdgcn_exp2f)
#define EXP2(x) __builtin_amdgcn_exp2f(x)
#else
#define EXP2(x) exp2f(x)
#endif

__device__ inline unsigned short f2b(float f) {
    union { float f; unsigned u; } v; v.f = f;
    unsigned r = v.u + 0x7fffu + ((v.u >> 16) & 1u);
    return (unsigned short)(r >> 16);
}

__device__ inline float b2f(short s) {
    union { unsigned u; float f; } v;
    v.u = ((unsigned)(unsigned short)s) << 16;
    return v.f;
}

// pack 4 fp32 -> 4 bf16 (RNE) via packed cvt
__device__ inline short4_t pk4(float p0, float p1, float p2, float p3) {
    union { __hip_bfloat162 h2[2]; short4_t s4; } u;
    u.h2[0] = __float22bfloat162_rn(make_float2(p0, p1));
    u.h2[1] = __float22bfloat162_rn(make_float2(p2, p3));
    return u.s4;
}

__device__ inline void gl2lds16(const void* g, void* l) {
    __builtin_amdgcn_global_load_lds(
        (const __attribute__((address_space(1))) unsigned int*)g,
        (__attribute__((address_space(3))) unsigned int*)l, 16, 0, 0);
}

// ---------------------------------------------------------------------------
// GEMM 128x128: C[M][N] = A[M][K](bf16) * BT[N][K](bf16)^T + bias
// EPI 0: bf16; EPI 1: fp32; EPI 2: GELU->bf16. Cols < scale_cols get *QSCALE.
// ---------------------------------------------------------------------------
template<int EPI>
__global__ __launch_bounds__(256) void gemm_bt(
    const unsigned short* __restrict__ A, const unsigned short* __restrict__ BT,
    const float* __restrict__ bias, void* __restrict__ Cout,
    int M, int N, int K, int scale_cols)
{
    __shared__ __align__(16) unsigned short As[128*32];
    __shared__ __align__(16) unsigned short Bs[128*32];
    const int tid  = threadIdx.x;
    const int wave = tid >> 6, lane = tid & 63;
    const int wy = wave >> 1, wx = wave & 1;
    const int quad = lane >> 4, m16 = lane & 15;
    const int row0 = blockIdx.y * 128, n0 = blockIdx.x * 128;
    const int rdoff = (quad ^ ((m16 >> 1) & 3)) * 8;   // swizzled read chunk

    f32x4 acc[4][4];
#pragma unroll
    for (int i = 0; i < 4; i++)
#pragma unroll
        for (int j = 0; j < 4; j++) acc[i][j] = (f32x4){0.f,0.f,0.f,0.f};

    const int kIters = K >> 5;
    for (int kt = 0; kt < kIters; ++kt) {
        const int k0 = kt << 5;
#pragma unroll
        for (int it = 0; it < 2; ++it) {
            int g  = it*256 + tid;
            int r  = g >> 2;
            int c8 = (((g & 3) ^ ((g >> 3) & 3)) << 3);   // swizzled source chunk
            gl2lds16(A  + (size_t)(row0 + r)*K + k0 + c8, &As[(size_t)(it*256 + wave*64)*8]);
            gl2lds16(BT + (size_t)(n0  + r)*K + k0 + c8, &Bs[(size_t)(it*256 + wave*64)*8]);
        }
        __syncthreads();
        short8 a[4], b[4];
#pragma unroll
        for (int i = 0; i < 4; i++) a[i] = *(const short8*)&As[(wy*64 + i*16 + m16)*32 + rdoff];
#pragma unroll
        for (int j = 0; j < 4; j++) b[j] = *(const short8*)&Bs[(wx*64 + j*16 + m16)*32 + rdoff];
#pragma unroll
        for (int i = 0; i < 4; i++)
#pragma unroll
            for (int j = 0; j < 4; j++)
                acc[i][j] = __builtin_amdgcn_mfma_f32_16x16x32_bf16(a[i], b[j], acc[i][j], 0, 0, 0);
        __syncthreads();
    }

#pragma unroll
    for (int j = 0; j < 4; j++) {
        int col = n0 + wx*64 + j*16 + m16;
        float bj = bias[col];
        float sc = (col < scale_cols) ? QSCALE : 1.0f;
#pragma unroll
        for (int i = 0; i < 4; i++) {
            int rbase = row0 + wy*64 + i*16 + quad*4;
#pragma unroll
            for (int r = 0; r < 4; r++) {
                float v = (acc[i][j][r] + bj) * sc;
                size_t idx = (size_t)(rbase + r)*N + col;
                if (EPI == 0) {
                    ((unsigned short*)Cout)[idx] = f2b(v);
                } else if (EPI == 1) {
                    ((float*)Cout)[idx] = v;
                } else {
                    float gv = 0.5f * v * (1.0f + erff(v * 0.70710678118654752f));
                    ((unsigned short*)Cout)[idx] = f2b(gv);
                }
            }
        }
    }
}

// ---------------------------------------------------------------------------
// GEMM 64x128 tile (for N=512 matmuls: doubles grid to 512 blocks)
// ---------------------------------------------------------------------------
template<int EPI>
__global__ __launch_bounds__(256) void gemm_bt64(
    const unsigned short* __restrict__ A, const unsigned short* __restrict__ BT,
    const float* __restrict__ bias, void* __restrict__ Cout,
    int M, int N, int K, int scale_cols)
{
    __shared__ __align__(16) unsigned short As[64*32];
    __shared__ __align__(16) unsigned short Bs[128*32];
    const int tid  = threadIdx.x;
    const int wave = tid >> 6, lane = tid & 63;
    const int wy = wave >> 1, wx = wave & 1;
    const int quad = lane >> 4, m16 = lane & 15;
    const int row0 = blockIdx.y * 64, n0 = blockIdx.x * 128;
    const int rdoff = (quad ^ ((m16 >> 1) & 3)) * 8;

    f32x4 acc[2][4];
#pragma unroll
    for (int i = 0; i < 2; i++)
#pragma unroll
        for (int j = 0; j < 4; j++) acc[i][j] = (f32x4){0.f,0.f,0.f,0.f};

    const int kIters = K >> 5;
    for (int kt = 0; kt < kIters; ++kt) {
        const int k0 = kt << 5;
        {
            int r = tid >> 2;
            int c8 = (((tid & 3) ^ ((tid >> 3) & 3)) << 3);
            gl2lds16(A + (size_t)(row0 + r)*K + k0 + c8, &As[(size_t)(wave*64)*8]);
        }
#pragma unroll
        for (int it = 0; it < 2; ++it) {
            int g  = it*256 + tid;
            int r  = g >> 2;
            int c8 = (((g & 3) ^ ((g >> 3) & 3)) << 3);
            gl2lds16(BT + (size_t)(n0 + r)*K + k0 + c8, &Bs[(size_t)(it*256 + wave*64)*8]);
        }
        __syncthreads();
        short8 a[2], b[4];
#pragma unroll
        for (int i = 0; i < 2; i++) a[i] = *(const short8*)&As[(wy*32 + i*16 + m16)*32 + rdoff];
#pragma unroll
        for (int j = 0; j < 4; j++) b[j] = *(const short8*)&Bs[(wx*64 + j*16 + m16)*32 + rdoff];
#pragma unroll
        for (int i = 0; i < 2; i++)
#pragma unroll
            for (int j = 0; j < 4; j++)
                acc[i][j] = __builtin_amdgcn_mfma_f32_16x16x32_bf16(a[i], b[j], acc[i][j], 0, 0, 0);
        __syncthreads();
    }

#pragma unroll
    for (int j = 0; j < 4; j++) {
        int col = n0 + wx*64 + j*16 + m16;
        float bj = bias[col];
        float sc = (col < scale_cols) ? QSCALE : 1.0f;
#pragma unroll
        for (int i = 0; i < 2; i++) {
            int rbase = row0 + wy*32 + i*16 + quad*4;
#pragma unroll
            for (int r = 0; r < 4; r++) {
                float v = (acc[i][j][r] + bj) * sc;
                size_t idx = (size_t)(rbase + r)*N + col;
                if (EPI == 0) {
                    ((unsigned short*)Cout)[idx] = f2b(v);
                } else if (EPI == 1) {
                    ((float*)Cout)[idx] = v;
                } else {
                    float gv = 0.5f * v * (1.0f + erff(v * 0.70710678118654752f));
                    ((unsigned short*)Cout)[idx] = f2b(gv);
                }
            }
        }
    }
}

// ---------------------------------------------------------------------------
// Repack Q,K from fused QKV [8192][1536] into per-head [bh][SEQ][64].
// ---------------------------------------------------------------------------
__global__ __launch_bounds__(256) void repack_qk(
    const unsigned short* __restrict__ QKV,
    unsigned short* __restrict__ Qp, unsigned short* __restrict__ Kp)
{
    const int bh = blockIdx.y, b = bh >> 3, h = bh & 7;
    const int l0 = blockIdx.x * 64;
    const int t = threadIdx.x;
    const int row = t >> 2, c = (t & 3) * 16;
    const unsigned short* src = QKV + (size_t)(b*SEQ + l0 + row)*1536 + h*64 + c;
    const size_t dst = ((size_t)bh*SEQ + l0 + row)*64 + c;
    *(short8*)&Qp[dst]   = *(const short8*)(src);
    *(short8*)&Qp[dst+8] = *(const short8*)(src + 8);
    *(short8*)&Kp[dst]   = *(const short8*)(src + 512);
    *(short8*)&Kp[dst+8] = *(const short8*)(src + 520);
}

// ---------------------------------------------------------------------------
// V (cols 1024..1535 of QKV) -> Vp [bh][kt][quad][64 d][32 key] where the 32
// keys of region `quad` are {nj*16 + quad*4 + r : nj 0..7, r 0..3} stored at
// nj*4+r. This is exactly the per-lane K16 A-fragment order -> flash reads V
// as b128. grid (32 kt, 16 bh), 256 threads.
// ---------------------------------------------------------------------------
__global__ __launch_bounds__(256) void transpose_v2(
    const unsigned short* __restrict__ QKV, unsigned short* __restrict__ Vp)
{
    __shared__ unsigned short Ls[128][66];
    const int kt = blockIdx.x, bh = blockIdx.y, b = bh >> 3, h = bh & 7;
    const int t = threadIdx.x;
    // read: 128 key-rows x 64 d
    {
        int key = t >> 1, dhalf = (t & 1) * 32;
        const unsigned short* src =
            QKV + (size_t)(b*SEQ + kt*128 + key)*1536 + 1024 + h*64 + dhalf;
#pragma unroll
        for (int c = 0; c < 4; ++c)
            *(short8*)&Ls[key][dhalf + c*8] = *(const short8*)(src + c*8);
    }
    __syncthreads();
    // write: region quad = t>>6, d = t&63 -> 32 keys in fragment order
    {
        int quad = t >> 6, d = t & 63;
        unsigned short tmp[32];
#pragma unroll
        for (int nj = 0; nj < 8; ++nj)
#pragma unroll
            for (int r = 0; r < 4; ++r)
                tmp[nj*4 + r] = Ls[nj*16 + quad*4 + r][d];
        unsigned short* dst = Vp + ((((size_t)bh*32 + kt)*4 + quad)*64 + d)*32;
#pragma unroll
        for (int c = 0; c < 4; ++c)
            *(short8*)&dst[c*8] = *(const short8*)&tmp[c*8];
    }
}

// per-128-key-tile all-ones flags. 64 flags total.
__global__ void mask_flags_k(const int* __restrict__ mask, int* __restrict__ flags)
{
    int t = threadIdx.x;   // 64 threads
    const int* m = mask + t*128;
    int all = 1;
    for (int i = 0; i < 128; i += 4) {
        int4 v = *(const int4*)(m + i);
        all &= (v.x && v.y && v.z && v.w) ? 1 : 0;
    }
    flags[t] = all;
}

// kmax[bh] = max over keys of ||K_row||_2. grid 16, 256 threads.
__global__ __launch_bounds__(256) void kmax_k(
    const unsigned short* __restrict__ Kp, float* __restrict__ kmax)
{
    const int bh = blockIdx.x, t = threadIdx.x;
    const int wave = t >> 6, lane = t & 63;
    float mx = 0.f;
    for (int row = t; row < SEQ; row += 256) {
        const unsigned short* kp = Kp + ((size_t)bh*SEQ + row)*64;
        float s = 0.f;
#pragma unroll
        for (int c = 0; c < 8; ++c) {
            short8 v = *(const short8*)(kp + c*8);
#pragma unroll
            for (int j = 0; j < 8; ++j) { float f = b2f(v[j]); s += f*f; }
        }
        mx = fmaxf(mx, s);
    }
#pragma unroll
    for (int off = 32; off >= 1; off >>= 1)
        mx = fmaxf(mx, __shfl_xor(mx, off, 64));
    __shared__ float w[4];
    if (lane == 0) w[wave] = mx;
    __syncthreads();
    if (t == 0)
        kmax[bh] = sqrtf(fmaxf(fmaxf(w[0], w[1]), fmaxf(w[2], w[3])));
}

// ---------------------------------------------------------------------------
// Flash attention, fixed-bound softmax (no online max/rescale).
// grid (SEQ/64, B*H), 256 threads; each wave owns 16 q rows.
// M = |q_hat|*kmax[bh] >= any score (Cauchy-Schwarz, log2 domain) -> p=2^(s-M)
// directly; per-lane rs accumulated, reduced once at the end.
// ---------------------------------------------------------------------------
__global__ __launch_bounds__(256) void flash_attn(
    const unsigned short* __restrict__ Qp, const unsigned short* __restrict__ Kp,
    const unsigned short* __restrict__ Vp, const int* __restrict__ mask,
    const int* __restrict__ flags, const float* __restrict__ kmax,
    unsigned short* __restrict__ O)
{
    __shared__ __align__(16) unsigned short Ks[2][128*32];
    __shared__ __align__(16) unsigned short Vs[4][64*32];
    const int tid = threadIdx.x, wave = tid >> 6, lane = tid & 63;
    const int quad = lane >> 4, m16 = lane & 15;
    const int bh = blockIdx.y, b = bh >> 3, h = bh & 7;
    const int qbase = blockIdx.x * 64 + wave * 16;
    const int fsw = (m16 >> 1) & 3;                  // row-derived swizzle key
    const int koff = (quad ^ fsw) * 8;               // Ks b128 read offset

    const unsigned short* Qb = Qp + (size_t)bh*SEQ*64;
    const unsigned short* Kb = Kp + (size_t)bh*SEQ*64;
    const unsigned short* Vb = Vp + (size_t)bh*32*4*64*32;
    const int* mbase = mask + b*SEQ;
    const int* fbase = flags + b*(SEQ/128);

    short8 qf[2];
    {
        const unsigned short* qp = Qb + (size_t)(qbase + m16)*64 + quad*8;
        qf[0] = *(const short8*)qp;
        qf[1] = *(const short8*)(qp + 32);
    }
    // fixed softmax bound M (per q row; includes QSCALE via q_hat)
    float qn2 = 0.f;
#pragma unroll
    for (int j = 0; j < 8; ++j) {
        float f0 = b2f(qf[0][j]), f1 = b2f(qf[1][j]);
        qn2 += f0*f0 + f1*f1;
    }
    qn2 += __shfl_xor(qn2, 16, 64);
    qn2 += __shfl_xor(qn2, 32, 64);
    const float M = sqrtf(qn2) * kmax[bh];

    f32x4 accO[4];
#pragma unroll
    for (int dj = 0; dj < 4; dj++) accO[dj] = (f32x4){0.f,0.f,0.f,0.f};
    float rs = 0.f;

    for (int kt = 0; kt < SEQ/128; ++kt) {
        const int key0 = kt * 128;
        const int allones = fbase[kt];
        __syncthreads();   // all waves done reading previous tile
        // stage K tile: two [128][32] halves, source-chunk swizzled
#pragma unroll
        for (int it = 0; it < 2; ++it) {
            int g = it*256 + tid;
            int r = g >> 2;
            int c8 = (((g & 3) ^ ((g >> 3) & 3)) << 3);
            gl2lds16(Kb + (size_t)(key0 + r)*64 + c8,      &Ks[0][(it*256 + wave*64)*8]);
            gl2lds16(Kb + (size_t)(key0 + r)*64 + 32 + c8, &Ks[1][(it*256 + wave*64)*8]);
        }
        // stage V tile: plain copy of fragment-ordered Vp (4 quad regions)
        {
            int d = wave*16 + (lane >> 2), ch = lane & 3;
#pragma unroll
            for (int qr = 0; qr < 4; ++qr)
                gl2lds16(Vb + (((size_t)kt*4 + qr)*64 + d)*32 + ch*8,
                         &Vs[qr][wave*64*8]);
        }
        __syncthreads();   // staging drained

        // ---- QK^T -> p = 2^(s - M) fused per nj
        short4_t pb[8];
#pragma unroll
        for (int nj = 0; nj < 8; ++nj) {
            short8 k0 = *(const short8*)&Ks[0][(nj*16 + m16)*32 + koff];
            short8 k1 = *(const short8*)&Ks[1][(nj*16 + m16)*32 + koff];
            f32x4 c = (f32x4){0.f,0.f,0.f,0.f};
            c = __builtin_amdgcn_mfma_f32_16x16x32_bf16(k0, qf[0], c, 0, 0, 0);
            c = __builtin_amdgcn_mfma_f32_16x16x32_bf16(k1, qf[1], c, 0, 0, 0);
            if (!allones) {
                int4 mv = *(const int4*)(mbase + key0 + nj*16 + quad*4);
                c[0] = mv.x ? c[0] : -1e9f;
                c[1] = mv.y ? c[1] : -1e9f;
                c[2] = mv.z ? c[2] : -1e9f;
                c[3] = mv.w ? c[3] : -1e9f;
            }
            float p0 = EXP2(c[0] - M);
            float p1 = EXP2(c[1] - M);
            float p2 = EXP2(c[2] - M);
            float p3 = EXP2(c[3] - M);
            rs += (p0 + p1) + (p2 + p3);
            pb[nj] = pk4(p0, p1, p2, p3);
        }

        // ---- PV: O^T += V^T·P^T. b128 V reads; physical chunk l^fsw holds
        // logical chunk l^fsw -> pb indices follow the ADDRESS, loop var l
        // keeps pb indexing compile-time.
#pragma unroll
        for (int l = 0; l < 4; ++l) {
#pragma unroll
            for (int dj = 0; dj < 4; ++dj) {
                short8 vv = *(const short8*)
                    &Vs[quad][(dj*16 + m16)*32 + (l ^ fsw)*8];
                short4_t vlo = __builtin_shufflevector(vv, vv, 0, 1, 2, 3);
                short4_t vhi = __builtin_shufflevector(vv, vv, 4, 5, 6, 7);
                accO[dj] = MFMA_K16(vlo, pb[2*(l ^ fsw)],     accO[dj]);
                accO[dj] = MFMA_K16(vhi, pb[2*(l ^ fsw) + 1], accO[dj]);
            }
        }
    }

    // final l reduction (once)
    rs += __shfl_xor(rs, 16, 64);
    rs += __shfl_xor(rs, 32, 64);
    float rl = 1.0f / rs;
#pragma unroll
    for (int dj = 0; dj < 4; ++dj) {
        short4_t o = pk4(accO[dj][0]*rl, accO[dj][1]*rl,
                         accO[dj][2]*rl, accO[dj][3]*rl);
        *(short4_t*)&O[(size_t)(b*SEQ + qbase + m16)*D_EMBED
                       + h*HEAD_DIM + dj*16 + quad*4] = o;
    }
}

// ---------------------------------------------------------------------------
// y = LayerNorm(A + B)*g + be; A fp32, B bf16 -> fp32 Yf (and bf16 Yb if set)
// ---------------------------------------------------------------------------
__global__ __launch_bounds__(256) void ln_res(
    const float* __restrict__ A, const unsigned short* __restrict__ Bv,
    const float* __restrict__ g, const float* __restrict__ be,
    float* __restrict__ Yf, unsigned short* __restrict__ Yb)
{
    const int wave = threadIdx.x >> 6, lane = threadIdx.x & 63;
    const int row = blockIdx.x * 4 + wave;
    const float* ap = A + (size_t)row*512 + lane*8;
    short8 bv = *(const short8*)(Bv + (size_t)row*512 + lane*8);
    float v[8]; float s = 0.f;
#pragma unroll
    for (int j = 0; j < 8; j++) { v[j] = ap[j] + b2f(bv[j]); s += v[j]; }
#pragma unroll
    for (int off = 32; off >= 1; off >>= 1) s += __shfl_xor(s, off, 64);
    float mu = s * (1.f/512.f);
    float q = 0.f;
#pragma unroll
    for (int j = 0; j < 8; j++) { v[j] -= mu; q += v[j]*v[j]; }
#pragma unroll
    for (int off = 32; off >= 1; off >>= 1) q += __shfl_xor(q, off, 64);
    float rstd = rsqrtf(q * (1.f/512.f) + 1e-5f);
#pragma unroll
    for (int j = 0; j < 8; j++) {
        float y = v[j]*rstd*g[lane*8+j] + be[lane*8+j];
        if (Yf) Yf[(size_t)row*512 + lane*8 + j] = y;
        if (Yb) Yb[(size_t)row*512 + lane*8 + j] = f2b(y);
    }
}

__global__ __launch_bounds__(256) void cvt_f32_bf16(
    const float* __restrict__ X, unsigned short* __restrict__ Y, int n)
{
    int idx = (blockIdx.x * 256 + threadIdx.x) * 4;
    if (idx < n) {
        float4 v = *(const float4*)(X + idx);
        Y[idx+0] = f2b(v.x); Y[idx+1] = f2b(v.y);
        Y[idx+2] = f2b(v.z); Y[idx+3] = f2b(v.w);
    }
}

// W[K][N] fp32 -> WT[N][K] bf16. block (32,8), grid (N/32, K/32)
__global__ void transpose_w(const float* __restrict__ W, unsigned short* __restrict__ WT,
                            int K, int N)
{
    __shared__ float t[32][33];
    int n0 = blockIdx.x*32, k0 = blockIdx.y*32;
    int x = threadIdx.x, y = threadIdx.y;
#pragma unroll
    for (int yy = y; yy < 32; yy += 8) t[yy][x] = W[(size_t)(k0+yy)*N + n0 + x];
    __syncthreads();
#pragma unroll
    for (int yy = y; yy < 32; yy += 8) WT[(size_t)(n0+yy)*K + k0 + x] = f2b(t[x][yy]);
}

__global__ void concat3(const float* __restrict__ a, const float* __restrict__ b,
                        const float* __restrict__ c, float* __restrict__ o)
{
    int i = blockIdx.x*256 + threadIdx.x;  // 1536 total
    o[i] = (i < 512) ? a[i] : ((i < 1024) ? b[i-512] : c[i-1024]);
}

extern "C" void kernel_launch(void* const* d_in, const int* in_sizes, int n_in,
                              void* d_out, int out_size, void* d_ws, size_t ws_size,
                              hipStream_t stream)
{
    const float* x    = (const float*)d_in[0];
    const int*   mask = (const int*)  d_in[1];
    const float* Wq = (const float*)d_in[2];  const float* bq = (const float*)d_in[3];
    const float* Wk = (const float*)d_in[4];  const float* bk = (const float*)d_in[5];
    const float* Wv = (const float*)d_in[6];  const float* bv = (const float*)d_in[7];
    const float* Wo = (const float*)d_in[8];  const float* bo = (const float*)d_in[9];
    const float* ln1g = (const float*)d_in[10]; const float* ln1b = (const float*)d_in[11];
    const float* ln2g = (const float*)d_in[12]; const float* ln2b = (const float*)d_in[13];
    const float* W1 = (const float*)d_in[14]; const float* b1 = (const float*)d_in[15];
    const float* W2 = (const float*)d_in[16]; const float* b2 = (const float*)d_in[17];
    float* out = (float*)d_out;

    char* ws = (char*)d_ws;
    const size_t MB = 1024*1024;
    // liveness-planned map (peak 79 MB):
    unsigned short* xb    = (unsigned short*)(ws + 0);           // 0..8, dead after QKV GEMM
    unsigned short* WqkvT = (unsigned short*)(ws + 8*MB);        // 8..9.5
    unsigned short* W1T   = (unsigned short*)(ws + 10*MB);       // 10..12
    unsigned short* W2T   = (unsigned short*)(ws + 12*MB);       // 12..14
    unsigned short* WoT   = (unsigned short*)(ws + 14*MB);       // 14..14.5
    float*          bqkv  = (float*)(ws + 14*MB + 512*1024);     // 6 KB
    int*            mflag = (int*)(ws + 14*MB + 768*1024);       // 256 B
    float*          kmaxb = (float*)(ws + 14*MB + 772*1024);     // 64 B
    unsigned short* QKVb  = (unsigned short*)(ws + 15*MB);       // 15..39, dead after repack/transpose
    unsigned short* Qp    = (unsigned short*)(ws + 39*MB);       // 39..47, dead after flash
    unsigned short* Kp    = (unsigned short*)(ws + 47*MB);       // 47..55, dead after flash
    unsigned short* Vp    = (unsigned short*)(ws + 55*MB);       // 55..63, dead after flash
    unsigned short* ctx   = (unsigned short*)(ws + 63*MB);       // 63..71, dead after Wo GEMM
    unsigned short* atfb  = (unsigned short*)(ws + 15*MB);       // 15..23 bf16, overlays dead QKVb
    unsigned short* ffb   = (unsigned short*)(ws + 23*MB);       // 23..31 bf16, overlays dead QKVb
    float*          hf    = (float*)(ws + 31*MB);                // 31..47, overlays dead QKVb/Qp
    unsigned short* hb    = (unsigned short*)(ws + 0);           // 0..8, overlays dead xb
    unsigned short* Gb    = (unsigned short*)(ws + 47*MB);       // 47..79, overlays dead Kp/Vp/ctx

    dim3 tb(32, 8);
    cvt_f32_bf16<<<4096, 256, 0, stream>>>(x, xb, M_ROWS*D_EMBED);
    transpose_w<<<dim3(16,16), tb, 0, stream>>>(Wq, WqkvT,            512, 512);
    transpose_w<<<dim3(16,16), tb, 0, stream>>>(Wk, WqkvT + 512*512,  512, 512);
    transpose_w<<<dim3(16,16), tb, 0, stream>>>(Wv, WqkvT + 1024*512, 512, 512);
    transpose_w<<<dim3(16,16), tb, 0, stream>>>(Wo, WoT, 512, 512);
    transpose_w<<<dim3(64,16), tb, 0, stream>>>(W1, W1T, 512, 2048);
    transpose_w<<<dim3(16,64), tb, 0, stream>>>(W2, W2T, 2048, 512);
    concat3<<<6, 256, 0, stream>>>(bq, bk, bv, bqkv);
    mask_flags_k<<<1, 64, 0, stream>>>(mask, mflag);

    // fused QKV projection, Q pre-scaled by QSCALE (0.125*log2e)
    gemm_bt<0><<<dim3(12,64), 256, 0, stream>>>(xb, WqkvT, bqkv, QKVb, M_ROWS, 1536, 512, 512);

    repack_qk<<<dim3(SEQ/64, 16), 256, 0, stream>>>(QKVb, Qp, Kp);
    transpose_v2<<<dim3(32, 16), 256, 0, stream>>>(QKVb, Vp);
    kmax_k<<<16, 256, 0, stream>>>(Kp, kmaxb);
    flash_attn<<<dim3(SEQ/64, 16), 256, 0, stream>>>(Qp, Kp, Vp, mask, mflag, kmaxb, ctx);

    gemm_bt64<0><<<dim3(4,128), 256, 0, stream>>>(ctx, WoT, bo, atfb, M_ROWS, 512, 512, 0);
    ln_res<<<M_ROWS/4, 256, 0, stream>>>(x, atfb, ln1g, ln1b, hf, hb);

    gemm_bt<2><<<dim3(16,64), 256, 0, stream>>>(hb, W1T, b1, Gb, M_ROWS, D_FF, 512, 0);
    gemm_bt64<0><<<dim3(4,128), 256, 0, stream>>>(Gb, W2T, b2, ffb, M_ROWS, 512, D_FF, 0);
    ln_res<<<M_ROWS/4, 256, 0, stream>>>(hf, ffb, ln2g, ln2b, out, (unsigned short*)nullptr);
}

// Round 9
// 431.410 us; speedup vs baseline: 2.0344x; 2.0344x over previous
//
#include <hip/hip_runtime.h>
#include <hip/hip_bf16.h>
#include <math.h>

#define D_EMBED 512
#define NUM_HEADS 8
#define HEAD_DIM 64
#define D_FF 2048
#define BATCH 2
#define SEQ 4096
#define M_ROWS (BATCH*SEQ)   // 8192
// 0.125 * log2(e): folds softmax's exp->exp2 conversion into the Q projection
#define QSCALE 0.18033688011112042f

typedef __attribute__((ext_vector_type(8))) short short8;
typedef __attribute__((ext_vector_type(4))) short short4_t;
typedef __attribute__((ext_vector_type(4))) float f32x4;

#if __has_builtin(__builtin_amdgcn_mfma_f32_16x16x16bf16_1k)
#define MFMA_K16(a,b,c) __builtin_amdgcn_mfma_f32_16x16x16bf16_1k(a,b,c,0,0,0)
#elif __has_builtin(__builtin_amdgcn_mfma_f32_16x16x16_bf16)
#define MFMA_K16(a,b,c) __builtin_amdgcn_mfma_f32_16x16x16_bf16(a,b,c,0,0,0)
#else
#define MFMA_K16(a,b,c) (c)   // host-pass parse stub
#endif

#if __has_builtin(__builtin_amdgcn_exp2f)
#define EXP2(x) __builtin_amdgcn_exp2f(x)
#else
#define EXP2(x) exp2f(x)
#endif

__device__ inline unsigned short f2b(float f) {
    union { float f; unsigned u; } v; v.f = f;
    unsigned r = v.u + 0x7fffu + ((v.u >> 16) & 1u);
    return (unsigned short)(r >> 16);
}

__device__ inline float b2f(short s) {
    union { unsigned u; float f; } v;
    v.u = ((unsigned)(unsigned short)s) << 16;
    return v.f;
}

// pack 4 fp32 -> 4 bf16 (RNE) via packed cvt
__device__ inline short4_t pk4(float p0, float p1, float p2, float p3) {
    union { __hip_bfloat162 h2[2]; short4_t s4; } u;
    u.h2[0] = __float22bfloat162_rn(make_float2(p0, p1));
    u.h2[1] = __float22bfloat162_rn(make_float2(p2, p3));
    return u.s4;
}

__device__ inline void gl2lds16(const void* g, void* l) {
    __builtin_amdgcn_global_load_lds(
        (const __attribute__((address_space(1))) unsigned int*)g,
        (__attribute__((address_space(3))) unsigned int*)l, 16, 0, 0);
}

// ---------------------------------------------------------------------------
// GEMM 128x128: C[M][N] = A[M][K](bf16) * BT[N][K](bf16)^T + bias
// EPI 0: bf16; EPI 1: fp32; EPI 2: GELU->bf16. Cols < scale_cols get *QSCALE.
// ---------------------------------------------------------------------------
template<int EPI>
__global__ __launch_bounds__(256) void gemm_bt(
    const unsigned short* __restrict__ A, const unsigned short* __restrict__ BT,
    const float* __restrict__ bias, void* __restrict__ Cout,
    int M, int N, int K, int scale_cols)
{
    __shared__ __align__(16) unsigned short As[128*32];
    __shared__ __align__(16) unsigned short Bs[128*32];
    const int tid  = threadIdx.x;
    const int wave = tid >> 6, lane = tid & 63;
    const int wy = wave >> 1, wx = wave & 1;
    const int quad = lane >> 4, m16 = lane & 15;
    const int row0 = blockIdx.y * 128, n0 = blockIdx.x * 128;
    const int rdoff = (quad ^ ((m16 >> 1) & 3)) * 8;   // swizzled read chunk

    f32x4 acc[4][4];
#pragma unroll
    for (int i = 0; i < 4; i++)
#pragma unroll
        for (int j = 0; j < 4; j++) acc[i][j] = (f32x4){0.f,0.f,0.f,0.f};

    const int kIters = K >> 5;
    for (int kt = 0; kt < kIters; ++kt) {
        const int k0 = kt << 5;
#pragma unroll
        for (int it = 0; it < 2; ++it) {
            int g  = it*256 + tid;
            int r  = g >> 2;
            int c8 = (((g & 3) ^ ((g >> 3) & 3)) << 3);   // swizzled source chunk
            gl2lds16(A  + (size_t)(row0 + r)*K + k0 + c8, &As[(size_t)(it*256 + wave*64)*8]);
            gl2lds16(BT + (size_t)(n0  + r)*K + k0 + c8, &Bs[(size_t)(it*256 + wave*64)*8]);
        }
        __syncthreads();
        short8 a[4], b[4];
#pragma unroll
        for (int i = 0; i < 4; i++) a[i] = *(const short8*)&As[(wy*64 + i*16 + m16)*32 + rdoff];
#pragma unroll
        for (int j = 0; j < 4; j++) b[j] = *(const short8*)&Bs[(wx*64 + j*16 + m16)*32 + rdoff];
#pragma unroll
        for (int i = 0; i < 4; i++)
#pragma unroll
            for (int j = 0; j < 4; j++)
                acc[i][j] = __builtin_amdgcn_mfma_f32_16x16x32_bf16(a[i], b[j], acc[i][j], 0, 0, 0);
        __syncthreads();
    }

#pragma unroll
    for (int j = 0; j < 4; j++) {
        int col = n0 + wx*64 + j*16 + m16;
        float bj = bias[col];
        float sc = (col < scale_cols) ? QSCALE : 1.0f;
#pragma unroll
        for (int i = 0; i < 4; i++) {
            int rbase = row0 + wy*64 + i*16 + quad*4;
#pragma unroll
            for (int r = 0; r < 4; r++) {
                float v = (acc[i][j][r] + bj) * sc;
                size_t idx = (size_t)(rbase + r)*N + col;
                if (EPI == 0) {
                    ((unsigned short*)Cout)[idx] = f2b(v);
                } else if (EPI == 1) {
                    ((float*)Cout)[idx] = v;
                } else {
                    float gv = 0.5f * v * (1.0f + erff(v * 0.70710678118654752f));
                    ((unsigned short*)Cout)[idx] = f2b(gv);
                }
            }
        }
    }
}

// ---------------------------------------------------------------------------
// GEMM 64x128 tile (for N=512 matmuls: doubles grid to 512 blocks)
// ---------------------------------------------------------------------------
template<int EPI>
__global__ __launch_bounds__(256) void gemm_bt64(
    const unsigned short* __restrict__ A, const unsigned short* __restrict__ BT,
    const float* __restrict__ bias, void* __restrict__ Cout,
    int M, int N, int K, int scale_cols)
{
    __shared__ __align__(16) unsigned short As[64*32];
    __shared__ __align__(16) unsigned short Bs[128*32];
    const int tid  = threadIdx.x;
    const int wave = tid >> 6, lane = tid & 63;
    const int wy = wave >> 1, wx = wave & 1;
    const int quad = lane >> 4, m16 = lane & 15;
    const int row0 = blockIdx.y * 64, n0 = blockIdx.x * 128;
    const int rdoff = (quad ^ ((m16 >> 1) & 3)) * 8;

    f32x4 acc[2][4];
#pragma unroll
    for (int i = 0; i < 2; i++)
#pragma unroll
        for (int j = 0; j < 4; j++) acc[i][j] = (f32x4){0.f,0.f,0.f,0.f};

    const int kIters = K >> 5;
    for (int kt = 0; kt < kIters; ++kt) {
        const int k0 = kt << 5;
        {
            int r = tid >> 2;
            int c8 = (((tid & 3) ^ ((tid >> 3) & 3)) << 3);
            gl2lds16(A + (size_t)(row0 + r)*K + k0 + c8, &As[(size_t)(wave*64)*8]);
        }
#pragma unroll
        for (int it = 0; it < 2; ++it) {
            int g  = it*256 + tid;
            int r  = g >> 2;
            int c8 = (((g & 3) ^ ((g >> 3) & 3)) << 3);
            gl2lds16(BT + (size_t)(n0 + r)*K + k0 + c8, &Bs[(size_t)(it*256 + wave*64)*8]);
        }
        __syncthreads();
        short8 a[2], b[4];
#pragma unroll
        for (int i = 0; i < 2; i++) a[i] = *(const short8*)&As[(wy*32 + i*16 + m16)*32 + rdoff];
#pragma unroll
        for (int j = 0; j < 4; j++) b[j] = *(const short8*)&Bs[(wx*64 + j*16 + m16)*32 + rdoff];
#pragma unroll
        for (int i = 0; i < 2; i++)
#pragma unroll
            for (int j = 0; j < 4; j++)
                acc[i][j] = __builtin_amdgcn_mfma_f32_16x16x32_bf16(a[i], b[j], acc[i][j], 0, 0, 0);
        __syncthreads();
    }

#pragma unroll
    for (int j = 0; j < 4; j++) {
        int col = n0 + wx*64 + j*16 + m16;
        float bj = bias[col];
        float sc = (col < scale_cols) ? QSCALE : 1.0f;
#pragma unroll
        for (int i = 0; i < 2; i++) {
            int rbase = row0 + wy*32 + i*16 + quad*4;
#pragma unroll
            for (int r = 0; r < 4; r++) {
                float v = (acc[i][j][r] + bj) * sc;
                size_t idx = (size_t)(rbase + r)*N + col;
                if (EPI == 0) {
                    ((unsigned short*)Cout)[idx] = f2b(v);
                } else if (EPI == 1) {
                    ((float*)Cout)[idx] = v;
                } else {
                    float gv = 0.5f * v * (1.0f + erff(v * 0.70710678118654752f));
                    ((unsigned short*)Cout)[idx] = f2b(gv);
                }
            }
        }
    }
}

// ---------------------------------------------------------------------------
// Repack Q,K from fused QKV [8192][1536] into per-head [bh][SEQ][64].
// ---------------------------------------------------------------------------
__global__ __launch_bounds__(256) void repack_qk(
    const unsigned short* __restrict__ QKV,
    unsigned short* __restrict__ Qp, unsigned short* __restrict__ Kp)
{
    const int bh = blockIdx.y, b = bh >> 3, h = bh & 7;
    const int l0 = blockIdx.x * 64;
    const int t = threadIdx.x;
    const int row = t >> 2, c = (t & 3) * 16;
    const unsigned short* src = QKV + (size_t)(b*SEQ + l0 + row)*1536 + h*64 + c;
    const size_t dst = ((size_t)bh*SEQ + l0 + row)*64 + c;
    *(short8*)&Qp[dst]   = *(const short8*)(src);
    *(short8*)&Qp[dst+8] = *(const short8*)(src + 8);
    *(short8*)&Kp[dst]   = *(const short8*)(src + 512);
    *(short8*)&Kp[dst+8] = *(const short8*)(src + 520);
}

// ---------------------------------------------------------------------------
// V (cols 1024..1535 of QKV) -> Vp [bh][kt][quad][64 d][32 key] where the 32
// keys of region `quad` are {nj*16 + quad*4 + r : nj 0..7, r 0..3} stored at
// nj*4+r (the per-lane K16 A-fragment order). grid (32 kt, 16 bh).
// ---------------------------------------------------------------------------
__global__ __launch_bounds__(256) void transpose_v2(
    const unsigned short* __restrict__ QKV, unsigned short* __restrict__ Vp)
{
    __shared__ unsigned short Ls[128][66];
    const int kt = blockIdx.x, bh = blockIdx.y, b = bh >> 3, h = bh & 7;
    const int t = threadIdx.x;
    {
        int key = t >> 1, dhalf = (t & 1) * 32;
        const unsigned short* src =
            QKV + (size_t)(b*SEQ + kt*128 + key)*1536 + 1024 + h*64 + dhalf;
#pragma unroll
        for (int c = 0; c < 4; ++c)
            *(short8*)&Ls[key][dhalf + c*8] = *(const short8*)(src + c*8);
    }
    __syncthreads();
    {
        int quad = t >> 6, d = t & 63;
        unsigned short tmp[32];
#pragma unroll
        for (int nj = 0; nj < 8; ++nj)
#pragma unroll
            for (int r = 0; r < 4; ++r)
                tmp[nj*4 + r] = Ls[nj*16 + quad*4 + r][d];
        unsigned short* dst = Vp + ((((size_t)bh*32 + kt)*4 + quad)*64 + d)*32;
#pragma unroll
        for (int c = 0; c < 4; ++c)
            *(short8*)&dst[c*8] = *(const short8*)&tmp[c*8];
    }
}

// per-128-key-tile all-ones flags. 64 flags total.
__global__ void mask_flags_k(const int* __restrict__ mask, int* __restrict__ flags)
{
    int t = threadIdx.x;   // 64 threads
    const int* m = mask + t*128;
    int all = 1;
    for (int i = 0; i < 128; i += 4) {
        int4 v = *(const int4*)(m + i);
        all &= (v.x && v.y && v.z && v.w) ? 1 : 0;
    }
    flags[t] = all;
}

// kmax[bh] = max over keys of ||K_row||_2. grid 16, 256 threads.
__global__ __launch_bounds__(256) void kmax_k(
    const unsigned short* __restrict__ Kp, float* __restrict__ kmax)
{
    const int bh = blockIdx.x, t = threadIdx.x;
    const int wave = t >> 6, lane = t & 63;
    float mx = 0.f;
    for (int row = t; row < SEQ; row += 256) {
        const unsigned short* kp = Kp + ((size_t)bh*SEQ + row)*64;
        float s = 0.f;
#pragma unroll
        for (int c = 0; c < 8; ++c) {
            short8 v = *(const short8*)(kp + c*8);
#pragma unroll
            for (int j = 0; j < 8; ++j) { float f = b2f(v[j]); s += f*f; }
        }
        mx = fmaxf(mx, s);
    }
#pragma unroll
    for (int off = 32; off >= 1; off >>= 1)
        mx = fmaxf(mx, __shfl_xor(mx, off, 64));
    __shared__ float w[4];
    if (lane == 0) w[wave] = mx;
    __syncthreads();
    if (t == 0)
        kmax[bh] = sqrtf(fmaxf(fmaxf(w[0], w[1]), fmaxf(w[2], w[3])));
}

// ---------------------------------------------------------------------------
// Flash attention, fixed-bound softmax (no online max/rescale).
// grid (SEQ/64, B*H), 256 threads; each wave owns 16 q rows.
// M = |q_hat|*kmax[bh] >= any score (Cauchy-Schwarz, log2 domain); p=2^(s-M).
// V staged with per-ROW source-chunk XOR so PV reads are b128 with per-lane
// swizzle folded into the ADDRESS while pb[] indices stay compile-time
// (R8's per-lane register indexing was the 4x VALU regression).
// ---------------------------------------------------------------------------
__global__ __launch_bounds__(256) void flash_attn(
    const unsigned short* __restrict__ Qp, const unsigned short* __restrict__ Kp,
    const unsigned short* __restrict__ Vp, const int* __restrict__ mask,
    const int* __restrict__ flags, const float* __restrict__ kmax,
    unsigned short* __restrict__ O)
{
    __shared__ __align__(16) unsigned short Ks[2][128*32];
    __shared__ __align__(16) unsigned short Vs[4][64*32];
    const int tid = threadIdx.x, wave = tid >> 6, lane = tid & 63;
    const int quad = lane >> 4, m16 = lane & 15;
    const int bh = blockIdx.y, b = bh >> 3, h = bh & 7;
    const int qbase = blockIdx.x * 64 + wave * 16;
    const int fsw = (m16 >> 1) & 3;                  // row-derived swizzle key
    const int koff = (quad ^ fsw) * 8;               // Ks b128 read offset

    const unsigned short* Qb = Qp + (size_t)bh*SEQ*64;
    const unsigned short* Kb = Kp + (size_t)bh*SEQ*64;
    const unsigned short* Vb = Vp + (size_t)bh*32*4*64*32;
    const int* mbase = mask + b*SEQ;
    const int* fbase = flags + b*(SEQ/128);

    short8 qf[2];
    {
        const unsigned short* qp = Qb + (size_t)(qbase + m16)*64 + quad*8;
        qf[0] = *(const short8*)qp;
        qf[1] = *(const short8*)(qp + 32);
    }
    // fixed softmax bound M (per q row; includes QSCALE via q_hat)
    float qn2 = 0.f;
#pragma unroll
    for (int j = 0; j < 8; ++j) {
        float f0 = b2f(qf[0][j]), f1 = b2f(qf[1][j]);
        qn2 += f0*f0 + f1*f1;
    }
    qn2 += __shfl_xor(qn2, 16, 64);
    qn2 += __shfl_xor(qn2, 32, 64);
    const float M = sqrtf(qn2) * kmax[bh];

    f32x4 accO[4];
#pragma unroll
    for (int dj = 0; dj < 4; dj++) accO[dj] = (f32x4){0.f,0.f,0.f,0.f};
    float rs = 0.f;

    for (int kt = 0; kt < SEQ/128; ++kt) {
        const int key0 = kt * 128;
        const int allones = fbase[kt];
        __syncthreads();   // all waves done reading previous tile
        // stage K tile: two [128][32] halves, source-chunk swizzled
#pragma unroll
        for (int it = 0; it < 2; ++it) {
            int g = it*256 + tid;
            int r = g >> 2;
            int c8 = (((g & 3) ^ ((g >> 3) & 3)) << 3);
            gl2lds16(Kb + (size_t)(key0 + r)*64 + c8,      &Ks[0][(it*256 + wave*64)*8]);
            gl2lds16(Kb + (size_t)(key0 + r)*64 + 32 + c8, &Ks[1][(it*256 + wave*64)*8]);
        }
        // stage V tile: fragment-ordered Vp, per-row source-chunk swizzle
        {
            int d = wave*16 + (lane >> 2), ch = lane & 3;
            int c8 = (ch ^ ((d >> 1) & 3)) * 8;
#pragma unroll
            for (int qr = 0; qr < 4; ++qr)
                gl2lds16(Vb + (((size_t)kt*4 + qr)*64 + d)*32 + c8,
                         &Vs[qr][wave*64*8]);
        }
        __syncthreads();   // staging drained

        // ---- QK^T -> p = 2^(s - M) fused per nj
        short4_t pb[8];
#pragma unroll
        for (int nj = 0; nj < 8; ++nj) {
            short8 k0 = *(const short8*)&Ks[0][(nj*16 + m16)*32 + koff];
            short8 k1 = *(const short8*)&Ks[1][(nj*16 + m16)*32 + koff];
            f32x4 c = (f32x4){0.f,0.f,0.f,0.f};
            c = __builtin_amdgcn_mfma_f32_16x16x32_bf16(k0, qf[0], c, 0, 0, 0);
            c = __builtin_amdgcn_mfma_f32_16x16x32_bf16(k1, qf[1], c, 0, 0, 0);
            if (!allones) {
                int4 mv = *(const int4*)(mbase + key0 + nj*16 + quad*4);
                c[0] = mv.x ? c[0] : -1e9f;
                c[1] = mv.y ? c[1] : -1e9f;
                c[2] = mv.z ? c[2] : -1e9f;
                c[3] = mv.w ? c[3] : -1e9f;
            }
            float p0 = EXP2(c[0] - M);
            float p1 = EXP2(c[1] - M);
            float p2 = EXP2(c[2] - M);
            float p3 = EXP2(c[3] - M);
            rs += (p0 + p1) + (p2 + p3);
            pb[nj] = pk4(p0, p1, p2, p3);
        }

        // ---- PV: O^T += V^T·P^T. b128 V reads; per-lane swizzle is in the
        // ADDRESS only; pb indices are compile-time.
#pragma unroll
        for (int l = 0; l < 4; ++l) {
#pragma unroll
            for (int dj = 0; dj < 4; ++dj) {
                short8 vv = *(const short8*)
                    &Vs[quad][(dj*16 + m16)*32 + ((l ^ fsw) * 8)];
                short4_t vlo = __builtin_shufflevector(vv, vv, 0, 1, 2, 3);
                short4_t vhi = __builtin_shufflevector(vv, vv, 4, 5, 6, 7);
                accO[dj] = MFMA_K16(vlo, pb[2*l],     accO[dj]);
                accO[dj] = MFMA_K16(vhi, pb[2*l + 1], accO[dj]);
            }
        }
    }

    // final l reduction (once)
    rs += __shfl_xor(rs, 16, 64);
    rs += __shfl_xor(rs, 32, 64);
    float rl = 1.0f / rs;
#pragma unroll
    for (int dj = 0; dj < 4; ++dj) {
        short4_t o = pk4(accO[dj][0]*rl, accO[dj][1]*rl,
                         accO[dj][2]*rl, accO[dj][3]*rl);
        *(short4_t*)&O[(size_t)(b*SEQ + qbase + m16)*D_EMBED
                       + h*HEAD_DIM + dj*16 + quad*4] = o;
    }
}

// ---------------------------------------------------------------------------
// y = LayerNorm(A + B)*g + be; A fp32, B bf16 -> fp32 Yf (and bf16 Yb if set)
// ---------------------------------------------------------------------------
__global__ __launch_bounds__(256) void ln_res(
    const float* __restrict__ A, const unsigned short* __restrict__ Bv,
    const float* __restrict__ g, const float* __restrict__ be,
    float* __restrict__ Yf, unsigned short* __restrict__ Yb)
{
    const int wave = threadIdx.x >> 6, lane = threadIdx.x & 63;
    const int row = blockIdx.x * 4 + wave;
    const float* ap = A + (size_t)row*512 + lane*8;
    short8 bv = *(const short8*)(Bv + (size_t)row*512 + lane*8);
    float v[8]; float s = 0.f;
#pragma unroll
    for (int j = 0; j < 8; j++) { v[j] = ap[j] + b2f(bv[j]); s += v[j]; }
#pragma unroll
    for (int off = 32; off >= 1; off >>= 1) s += __shfl_xor(s, off, 64);
    float mu = s * (1.f/512.f);
    float q = 0.f;
#pragma unroll
    for (int j = 0; j < 8; j++) { v[j] -= mu; q += v[j]*v[j]; }
#pragma unroll
    for (int off = 32; off >= 1; off >>= 1) q += __shfl_xor(q, off, 64);
    float rstd = rsqrtf(q * (1.f/512.f) + 1e-5f);
#pragma unroll
    for (int j = 0; j < 8; j++) {
        float y = v[j]*rstd*g[lane*8+j] + be[lane*8+j];
        if (Yf) Yf[(size_t)row*512 + lane*8 + j] = y;
        if (Yb) Yb[(size_t)row*512 + lane*8 + j] = f2b(y);
    }
}

__global__ __launch_bounds__(256) void cvt_f32_bf16(
    const float* __restrict__ X, unsigned short* __restrict__ Y, int n)
{
    int idx = (blockIdx.x * 256 + threadIdx.x) * 4;
    if (idx < n) {
        float4 v = *(const float4*)(X + idx);
        Y[idx+0] = f2b(v.x); Y[idx+1] = f2b(v.y);
        Y[idx+2] = f2b(v.z); Y[idx+3] = f2b(v.w);
    }
}

// W[K][N] fp32 -> WT[N][K] bf16. block (32,8), grid (N/32, K/32)
__global__ void transpose_w(const float* __restrict__ W, unsigned short* __restrict__ WT,
                            int K, int N)
{
    __shared__ float t[32][33];
    int n0 = blockIdx.x*32, k0 = blockIdx.y*32;
    int x = threadIdx.x, y = threadIdx.y;
#pragma unroll
    for (int yy = y; yy < 32; yy += 8) t[yy][x] = W[(size_t)(k0+yy)*N + n0 + x];
    __syncthreads();
#pragma unroll
    for (int yy = y; yy < 32; yy += 8) WT[(size_t)(n0+yy)*K + k0 + x] = f2b(t[x][yy]);
}

__global__ void concat3(const float* __restrict__ a, const float* __restrict__ b,
                        const float* __restrict__ c, float* __restrict__ o)
{
    int i = blockIdx.x*256 + threadIdx.x;  // 1536 total
    o[i] = (i < 512) ? a[i] : ((i < 1024) ? b[i-512] : c[i-1024]);
}

extern "C" void kernel_launch(void* const* d_in, const int* in_sizes, int n_in,
                              void* d_out, int out_size, void* d_ws, size_t ws_size,
                              hipStream_t stream)
{
    const float* x    = (const float*)d_in[0];
    const int*   mask = (const int*)  d_in[1];
    const float* Wq = (const float*)d_in[2];  const float* bq = (const float*)d_in[3];
    const float* Wk = (const float*)d_in[4];  const float* bk = (const float*)d_in[5];
    const float* Wv = (const float*)d_in[6];  const float* bv = (const float*)d_in[7];
    const float* Wo = (const float*)d_in[8];  const float* bo = (const float*)d_in[9];
    const float* ln1g = (const float*)d_in[10]; const float* ln1b = (const float*)d_in[11];
    const float* ln2g = (const float*)d_in[12]; const float* ln2b = (const float*)d_in[13];
    const float* W1 = (const float*)d_in[14]; const float* b1 = (const float*)d_in[15];
    const float* W2 = (const float*)d_in[16]; const float* b2 = (const float*)d_in[17];
    float* out = (float*)d_out;

    char* ws = (char*)d_ws;
    const size_t MB = 1024*1024;
    // liveness-planned map (peak 79 MB):
    unsigned short* xb    = (unsigned short*)(ws + 0);           // 0..8, dead after QKV GEMM
    unsigned short* WqkvT = (unsigned short*)(ws + 8*MB);        // 8..9.5
    unsigned short* W1T   = (unsigned short*)(ws + 10*MB);       // 10..12
    unsigned short* W2T   = (unsigned short*)(ws + 12*MB);       // 12..14
    unsigned short* WoT   = (unsigned short*)(ws + 14*MB);       // 14..14.5
    float*          bqkv  = (float*)(ws + 14*MB + 512*1024);     // 6 KB
    int*            mflag = (int*)(ws + 14*MB + 768*1024);       // 256 B
    float*          kmaxb = (float*)(ws + 14*MB + 772*1024);     // 64 B
    unsigned short* QKVb  = (unsigned short*)(ws + 15*MB);       // 15..39, dead after repack/transpose
    unsigned short* Qp    = (unsigned short*)(ws + 39*MB);       // 39..47, dead after flash
    unsigned short* Kp    = (unsigned short*)(ws + 47*MB);       // 47..55, dead after flash
    unsigned short* Vp    = (unsigned short*)(ws + 55*MB);       // 55..63, dead after flash
    unsigned short* ctx   = (unsigned short*)(ws + 63*MB);       // 63..71, dead after Wo GEMM
    unsigned short* atfb  = (unsigned short*)(ws + 15*MB);       // 15..23 bf16, overlays dead QKVb
    unsigned short* ffb   = (unsigned short*)(ws + 23*MB);       // 23..31 bf16, overlays dead QKVb
    float*          hf    = (float*)(ws + 31*MB);                // 31..47, overlays dead QKVb/Qp
    unsigned short* hb    = (unsigned short*)(ws + 0);           // 0..8, overlays dead xb
    unsigned short* Gb    = (unsigned short*)(ws + 47*MB);       // 47..79, overlays dead Kp/Vp/ctx

    dim3 tb(32, 8);
    cvt_f32_bf16<<<4096, 256, 0, stream>>>(x, xb, M_ROWS*D_EMBED);
    transpose_w<<<dim3(16,16), tb, 0, stream>>>(Wq, WqkvT,            512, 512);
    transpose_w<<<dim3(16,16), tb, 0, stream>>>(Wk, WqkvT + 512*512,  512, 512);
    transpose_w<<<dim3(16,16), tb, 0, stream>>>(Wv, WqkvT + 1024*512, 512, 512);
    transpose_w<<<dim3(16,16), tb, 0, stream>>>(Wo, WoT, 512, 512);
    transpose_w<<<dim3(64,16), tb, 0, stream>>>(W1, W1T, 512, 2048);
    transpose_w<<<dim3(16,64), tb, 0, stream>>>(W2, W2T, 2048, 512);
    concat3<<<6, 256, 0, stream>>>(bq, bk, bv, bqkv);
    mask_flags_k<<<1, 64, 0, stream>>>(mask, mflag);

    // fused QKV projection, Q pre-scaled by QSCALE (0.125*log2e)
    gemm_bt<0><<<dim3(12,64), 256, 0, stream>>>(xb, WqkvT, bqkv, QKVb, M_ROWS, 1536, 512, 512);

    repack_qk<<<dim3(SEQ/64, 16), 256, 0, stream>>>(QKVb, Qp, Kp);
    transpose_v2<<<dim3(32, 16), 256, 0, stream>>>(QKVb, Vp);
    kmax_k<<<16, 256, 0, stream>>>(Kp, kmaxb);
    flash_attn<<<dim3(SEQ/64, 16), 256, 0, stream>>>(Qp, Kp, Vp, mask, mflag, kmaxb, ctx);

    gemm_bt64<0><<<dim3(4,128), 256, 0, stream>>>(ctx, WoT, bo, atfb, M_ROWS, 512, 512, 0);
    ln_res<<<M_ROWS/4, 256, 0, stream>>>(x, atfb, ln1g, ln1b, hf, hb);

    gemm_bt<2><<<dim3(16,64), 256, 0, stream>>>(hb, W1T, b1, Gb, M_ROWS, D_FF, 512, 0);
    gemm_bt64<0><<<dim3(4,128), 256, 0, stream>>>(Gb, W2T, b2, ffb, M_ROWS, 512, D_FF, 0);
    ln_res<<<M_ROWS/4, 256, 0, stream>>>(hf, ffb, ln2g, ln2b, out, (unsigned short*)nullptr);
}

// Round 10
// 427.877 us; speedup vs baseline: 2.0512x; 1.0083x over previous
//
#include <hip/hip_runtime.h>
#include <hip/hip_bf16.h>
#include <math.h>

#define D_EMBED 512
#define NUM_HEADS 8
#define HEAD_DIM 64
#define D_FF 2048
#define BATCH 2
#define SEQ 4096
#define M_ROWS (BATCH*SEQ)   // 8192
// 0.125 * log2(e): folds softmax's exp->exp2 conversion into the Q projection
#define QSCALE 0.18033688011112042f

typedef __attribute__((ext_vector_type(8))) short short8;
typedef __attribute__((ext_vector_type(4))) short short4_t;
typedef __attribute__((ext_vector_type(4))) float f32x4;

#if __has_builtin(__builtin_amdgcn_mfma_f32_16x16x16bf16_1k)
#define MFMA_K16(a,b,c) __builtin_amdgcn_mfma_f32_16x16x16bf16_1k(a,b,c,0,0,0)
#elif __has_builtin(__builtin_amdgcn_mfma_f32_16x16x16_bf16)
#define MFMA_K16(a,b,c) __builtin_amdgcn_mfma_f32_16x16x16_bf16(a,b,c,0,0,0)
#else
#define MFMA_K16(a,b,c) (c)   // host-pass parse stub
#endif

#if __has_builtin(__builtin_amdgcn_exp2f)
#define EXP2(x) __builtin_amdgcn_exp2f(x)
#else
#define EXP2(x) exp2f(x)
#endif

__device__ inline unsigned short f2b(float f) {
    union { float f; unsigned u; } v; v.f = f;
    unsigned r = v.u + 0x7fffu + ((v.u >> 16) & 1u);
    return (unsigned short)(r >> 16);
}

__device__ inline float b2f(short s) {
    union { unsigned u; float f; } v;
    v.u = ((unsigned)(unsigned short)s) << 16;
    return v.f;
}

// pack 4 fp32 -> 4 bf16 (RNE) via packed cvt
__device__ inline short4_t pk4(float p0, float p1, float p2, float p3) {
    union { __hip_bfloat162 h2[2]; short4_t s4; } u;
    u.h2[0] = __float22bfloat162_rn(make_float2(p0, p1));
    u.h2[1] = __float22bfloat162_rn(make_float2(p2, p3));
    return u.s4;
}

__device__ inline void gl2lds16(const void* g, void* l) {
    __builtin_amdgcn_global_load_lds(
        (const __attribute__((address_space(1))) unsigned int*)g,
        (__attribute__((address_space(3))) unsigned int*)l, 16, 0, 0);
}

// ---------------------------------------------------------------------------
// GEMM 128x128: C[M][N] = A[M][K](bf16) * BT[N][K](bf16)^T + bias
// EPI 0: bf16; EPI 2: GELU->bf16.
// ---------------------------------------------------------------------------
template<int EPI>
__global__ __launch_bounds__(256) void gemm_bt(
    const unsigned short* __restrict__ A, const unsigned short* __restrict__ BT,
    const float* __restrict__ bias, void* __restrict__ Cout,
    int M, int N, int K)
{
    __shared__ __align__(16) unsigned short As[128*32];
    __shared__ __align__(16) unsigned short Bs[128*32];
    const int tid  = threadIdx.x;
    const int wave = tid >> 6, lane = tid & 63;
    const int wy = wave >> 1, wx = wave & 1;
    const int quad = lane >> 4, m16 = lane & 15;
    const int row0 = blockIdx.y * 128, n0 = blockIdx.x * 128;
    const int rdoff = (quad ^ ((m16 >> 1) & 3)) * 8;   // swizzled read chunk

    f32x4 acc[4][4];
#pragma unroll
    for (int i = 0; i < 4; i++)
#pragma unroll
        for (int j = 0; j < 4; j++) acc[i][j] = (f32x4){0.f,0.f,0.f,0.f};

    const int kIters = K >> 5;
    for (int kt = 0; kt < kIters; ++kt) {
        const int k0 = kt << 5;
#pragma unroll
        for (int it = 0; it < 2; ++it) {
            int g  = it*256 + tid;
            int r  = g >> 2;
            int c8 = (((g & 3) ^ ((g >> 3) & 3)) << 3);   // swizzled source chunk
            gl2lds16(A  + (size_t)(row0 + r)*K + k0 + c8, &As[(size_t)(it*256 + wave*64)*8]);
            gl2lds16(BT + (size_t)(n0  + r)*K + k0 + c8, &Bs[(size_t)(it*256 + wave*64)*8]);
        }
        __syncthreads();
        short8 a[4], b[4];
#pragma unroll
        for (int i = 0; i < 4; i++) a[i] = *(const short8*)&As[(wy*64 + i*16 + m16)*32 + rdoff];
#pragma unroll
        for (int j = 0; j < 4; j++) b[j] = *(const short8*)&Bs[(wx*64 + j*16 + m16)*32 + rdoff];
#pragma unroll
        for (int i = 0; i < 4; i++)
#pragma unroll
            for (int j = 0; j < 4; j++)
                acc[i][j] = __builtin_amdgcn_mfma_f32_16x16x32_bf16(a[i], b[j], acc[i][j], 0, 0, 0);
        __syncthreads();
    }

#pragma unroll
    for (int j = 0; j < 4; j++) {
        int col = n0 + wx*64 + j*16 + m16;
        float bj = bias[col];
#pragma unroll
        for (int i = 0; i < 4; i++) {
            int rbase = row0 + wy*64 + i*16 + quad*4;
#pragma unroll
            for (int r = 0; r < 4; r++) {
                float v = acc[i][j][r] + bj;
                size_t idx = (size_t)(rbase + r)*N + col;
                if (EPI == 0) {
                    ((unsigned short*)Cout)[idx] = f2b(v);
                } else {
                    float gv = 0.5f * v * (1.0f + erff(v * 0.70710678118654752f));
                    ((unsigned short*)Cout)[idx] = f2b(gv);
                }
            }
        }
    }
}

// ---------------------------------------------------------------------------
// QKV GEMM: same K-loop, epilogue scatters directly into Qp/Kp/Vp layouts.
// Qp,Kp: [bh][SEQ][64]; Vp: [bh][kt][quad][64 d][32 key-frag].
// Q region pre-scaled by QSCALE. Region (Q/K/V) is uniform per block.
// ---------------------------------------------------------------------------
__global__ __launch_bounds__(256) void gemm_qkv(
    const unsigned short* __restrict__ A, const unsigned short* __restrict__ BT,
    const float* __restrict__ bias,
    unsigned short* __restrict__ Qp, unsigned short* __restrict__ Kp,
    unsigned short* __restrict__ Vp)
{
    const int K = 512, N = 1536;
    __shared__ __align__(16) unsigned short As[128*32];
    __shared__ __align__(16) unsigned short Bs[128*32];
    const int tid  = threadIdx.x;
    const int wave = tid >> 6, lane = tid & 63;
    const int wy = wave >> 1, wx = wave & 1;
    const int quad = lane >> 4, m16 = lane & 15;
    const int row0 = blockIdx.y * 128, n0 = blockIdx.x * 128;
    const int rdoff = (quad ^ ((m16 >> 1) & 3)) * 8;
    const int region = n0 >> 9;   // 0=Q, 1=K, 2=V (uniform per block)

    f32x4 acc[4][4];
#pragma unroll
    for (int i = 0; i < 4; i++)
#pragma unroll
        for (int j = 0; j < 4; j++) acc[i][j] = (f32x4){0.f,0.f,0.f,0.f};

    for (int kt = 0; kt < 16; ++kt) {
        const int k0 = kt << 5;
#pragma unroll
        for (int it = 0; it < 2; ++it) {
            int g  = it*256 + tid;
            int r  = g >> 2;
            int c8 = (((g & 3) ^ ((g >> 3) & 3)) << 3);
            gl2lds16(A  + (size_t)(row0 + r)*K + k0 + c8, &As[(size_t)(it*256 + wave*64)*8]);
            gl2lds16(BT + (size_t)(n0  + r)*K + k0 + c8, &Bs[(size_t)(it*256 + wave*64)*8]);
        }
        __syncthreads();
        short8 a[4], b[4];
#pragma unroll
        for (int i = 0; i < 4; i++) a[i] = *(const short8*)&As[(wy*64 + i*16 + m16)*32 + rdoff];
#pragma unroll
        for (int j = 0; j < 4; j++) b[j] = *(const short8*)&Bs[(wx*64 + j*16 + m16)*32 + rdoff];
#pragma unroll
        for (int i = 0; i < 4; i++)
#pragma unroll
            for (int j = 0; j < 4; j++)
                acc[i][j] = __builtin_amdgcn_mfma_f32_16x16x32_bf16(a[i], b[j], acc[i][j], 0, 0, 0);
        __syncthreads();
    }

    const float sc = (region == 0) ? QSCALE : 1.0f;
#pragma unroll
    for (int j = 0; j < 4; j++) {
        int col = n0 + wx*64 + j*16 + m16;
        float bj = bias[col];
        int cc = col & 511, h = cc >> 6, d = cc & 63;
#pragma unroll
        for (int i = 0; i < 4; i++) {
            int rbase = row0 + wy*64 + i*16 + quad*4;
#pragma unroll
            for (int r = 0; r < 4; r++) {
                float v = (acc[i][j][r] + bj) * sc;
                int row = rbase + r;
                int b = row >> 12, l = row & 4095;
                size_t bh = (size_t)(b*8 + h);
                if (region == 0) {
                    Qp[(bh*SEQ + l)*64 + d] = f2b(v);
                } else if (region == 1) {
                    Kp[(bh*SEQ + l)*64 + d] = f2b(v);
                } else {
                    int kt = l >> 7, kk = l & 127;
                    int qr = (kk >> 2) & 3, fi = (kk >> 4)*4 + (kk & 3);
                    Vp[((((bh*32 + kt)*4 + qr)*64 + d)*32) + fi] = f2b(v);
                }
            }
        }
    }
}

// ---------------------------------------------------------------------------
// GEMM 64x128 tile (N=512 matmuls: grid 512 blocks). EPI 0: bf16 out.
// ---------------------------------------------------------------------------
__global__ __launch_bounds__(256) void gemm_bt64(
    const unsigned short* __restrict__ A, const unsigned short* __restrict__ BT,
    const float* __restrict__ bias, unsigned short* __restrict__ Cout,
    int M, int N, int K)
{
    __shared__ __align__(16) unsigned short As[64*32];
    __shared__ __align__(16) unsigned short Bs[128*32];
    const int tid  = threadIdx.x;
    const int wave = tid >> 6, lane = tid & 63;
    const int wy = wave >> 1, wx = wave & 1;
    const int quad = lane >> 4, m16 = lane & 15;
    const int row0 = blockIdx.y * 64, n0 = blockIdx.x * 128;
    const int rdoff = (quad ^ ((m16 >> 1) & 3)) * 8;

    f32x4 acc[2][4];
#pragma unroll
    for (int i = 0; i < 2; i++)
#pragma unroll
        for (int j = 0; j < 4; j++) acc[i][j] = (f32x4){0.f,0.f,0.f,0.f};

    const int kIters = K >> 5;
    for (int kt = 0; kt < kIters; ++kt) {
        const int k0 = kt << 5;
        {
            int r = tid >> 2;
            int c8 = (((tid & 3) ^ ((tid >> 3) & 3)) << 3);
            gl2lds16(A + (size_t)(row0 + r)*K + k0 + c8, &As[(size_t)(wave*64)*8]);
        }
#pragma unroll
        for (int it = 0; it < 2; ++it) {
            int g  = it*256 + tid;
            int r  = g >> 2;
            int c8 = (((g & 3) ^ ((g >> 3) & 3)) << 3);
            gl2lds16(BT + (size_t)(n0 + r)*K + k0 + c8, &Bs[(size_t)(it*256 + wave*64)*8]);
        }
        __syncthreads();
        short8 a[2], b[4];
#pragma unroll
        for (int i = 0; i < 2; i++) a[i] = *(const short8*)&As[(wy*32 + i*16 + m16)*32 + rdoff];
#pragma unroll
        for (int j = 0; j < 4; j++) b[j] = *(const short8*)&Bs[(wx*64 + j*16 + m16)*32 + rdoff];
#pragma unroll
        for (int i = 0; i < 2; i++)
#pragma unroll
            for (int j = 0; j < 4; j++)
                acc[i][j] = __builtin_amdgcn_mfma_f32_16x16x32_bf16(a[i], b[j], acc[i][j], 0, 0, 0);
        __syncthreads();
    }

#pragma unroll
    for (int j = 0; j < 4; j++) {
        int col = n0 + wx*64 + j*16 + m16;
        float bj = bias[col];
#pragma unroll
        for (int i = 0; i < 2; i++) {
            int rbase = row0 + wy*32 + i*16 + quad*4;
#pragma unroll
            for (int r = 0; r < 4; r++) {
                float v = acc[i][j][r] + bj;
                Cout[(size_t)(rbase + r)*N + col] = f2b(v);
            }
        }
    }
}

// per-128-key-tile all-ones flags. 64 flags total.
__global__ void mask_flags_k(const int* __restrict__ mask, int* __restrict__ flags)
{
    int t = threadIdx.x;   // 64 threads
    const int* m = mask + t*128;
    int all = 1;
    for (int i = 0; i < 128; i += 4) {
        int4 v = *(const int4*)(m + i);
        all &= (v.x && v.y && v.z && v.w) ? 1 : 0;
    }
    flags[t] = all;
}

// kmax2[bh] = max_row ||K_row||^2, via atomicMax on positive-float bits.
// grid (16 bh, 16 slices), 256 threads; kmax2 must be zeroed beforehand.
__global__ __launch_bounds__(256) void kmax_k(
    const unsigned short* __restrict__ Kp, unsigned* __restrict__ kmax2)
{
    const int bh = blockIdx.x, t = threadIdx.x;
    const int row = blockIdx.y*256 + t;
    const unsigned short* kp = Kp + ((size_t)bh*SEQ + row)*64;
    float s = 0.f;
#pragma unroll
    for (int c = 0; c < 8; ++c) {
        short8 v = *(const short8*)(kp + c*8);
#pragma unroll
        for (int j = 0; j < 8; ++j) { float f = b2f(v[j]); s += f*f; }
    }
#pragma unroll
    for (int off = 32; off >= 1; off >>= 1)
        s = fmaxf(s, __shfl_xor(s, off, 64));
    if ((t & 63) == 0) atomicMax(&kmax2[bh], __float_as_uint(s));
}

// ---------------------------------------------------------------------------
// Flash attention, fixed-bound softmax. grid (SEQ/64, B*H), 256 threads.
// M = sqrt(|q_hat|^2 * kmax2[bh]) >= any score (Cauchy-Schwarz, log2 domain).
// V reads are two ds_read_b64 directly into K16 A-operands (no extraction).
// ---------------------------------------------------------------------------
__global__ __launch_bounds__(256) void flash_attn(
    const unsigned short* __restrict__ Qp, const unsigned short* __restrict__ Kp,
    const unsigned short* __restrict__ Vp, const int* __restrict__ mask,
    const int* __restrict__ flags, const unsigned* __restrict__ kmax2,
    unsigned short* __restrict__ O)
{
    __shared__ __align__(16) unsigned short Ks[2][128*32];
    __shared__ __align__(16) unsigned short Vs[4][64*32];
    const int tid = threadIdx.x, wave = tid >> 6, lane = tid & 63;
    const int quad = lane >> 4, m16 = lane & 15;
    const int bh = blockIdx.y, b = bh >> 3, h = bh & 7;
    const int qbase = blockIdx.x * 64 + wave * 16;
    const int fsw = (m16 >> 1) & 3;                  // row-derived swizzle key
    const int koff = (quad ^ fsw) * 8;               // Ks b128 read offset

    const unsigned short* Qb = Qp + (size_t)bh*SEQ*64;
    const unsigned short* Kb = Kp + (size_t)bh*SEQ*64;
    const unsigned short* Vb = Vp + (size_t)bh*32*4*64*32;
    const int* mbase = mask + b*SEQ;
    const int* fbase = flags + b*(SEQ/128);

    short8 qf[2];
    {
        const unsigned short* qp = Qb + (size_t)(qbase + m16)*64 + quad*8;
        qf[0] = *(const short8*)qp;
        qf[1] = *(const short8*)(qp + 32);
    }
    // fixed softmax bound M (per q row; includes QSCALE via q_hat)
    float qn2 = 0.f;
#pragma unroll
    for (int j = 0; j < 8; ++j) {
        float f0 = b2f(qf[0][j]), f1 = b2f(qf[1][j]);
        qn2 += f0*f0 + f1*f1;
    }
    qn2 += __shfl_xor(qn2, 16, 64);
    qn2 += __shfl_xor(qn2, 32, 64);
    const float M = sqrtf(qn2 * __uint_as_float(kmax2[bh]));

    f32x4 accO[4];
#pragma unroll
    for (int dj = 0; dj < 4; dj++) accO[dj] = (f32x4){0.f,0.f,0.f,0.f};
    float rs = 0.f;

    for (int kt = 0; kt < SEQ/128; ++kt) {
        const int key0 = kt * 128;
        const int allones = fbase[kt];
        __syncthreads();   // all waves done reading previous tile
        // stage K tile: two [128][32] halves, source-chunk swizzled
#pragma unroll
        for (int it = 0; it < 2; ++it) {
            int g = it*256 + tid;
            int r = g >> 2;
            int c8 = (((g & 3) ^ ((g >> 3) & 3)) << 3);
            gl2lds16(Kb + (size_t)(key0 + r)*64 + c8,      &Ks[0][(it*256 + wave*64)*8]);
            gl2lds16(Kb + (size_t)(key0 + r)*64 + 32 + c8, &Ks[1][(it*256 + wave*64)*8]);
        }
        // stage V tile: fragment-ordered Vp, per-row source-chunk swizzle
        {
            int d = wave*16 + (lane >> 2), ch = lane & 3;
            int c8 = (ch ^ ((d >> 1) & 3)) * 8;
#pragma unroll
            for (int qr = 0; qr < 4; ++qr)
                gl2lds16(Vb + (((size_t)kt*4 + qr)*64 + d)*32 + c8,
                         &Vs[qr][wave*64*8]);
        }
        __syncthreads();   // staging drained

        // ---- QK^T -> p = 2^(s - M) fused per nj
        short4_t pb[8];
#pragma unroll
        for (int nj = 0; nj < 8; ++nj) {
            short8 k0 = *(const short8*)&Ks[0][(nj*16 + m16)*32 + koff];
            short8 k1 = *(const short8*)&Ks[1][(nj*16 + m16)*32 + koff];
            f32x4 c = (f32x4){0.f,0.f,0.f,0.f};
            c = __builtin_amdgcn_mfma_f32_16x16x32_bf16(k0, qf[0], c, 0, 0, 0);
            c = __builtin_amdgcn_mfma_f32_16x16x32_bf16(k1, qf[1], c, 0, 0, 0);
            if (!allones) {
                int4 mv = *(const int4*)(mbase + key0 + nj*16 + quad*4);
                c[0] = mv.x ? c[0] : -1e9f;
                c[1] = mv.y ? c[1] : -1e9f;
                c[2] = mv.z ? c[2] : -1e9f;
                c[3] = mv.w ? c[3] : -1e9f;
            }
            float p0 = EXP2(c[0] - M);
            float p1 = EXP2(c[1] - M);
            float p2 = EXP2(c[2] - M);
            float p3 = EXP2(c[3] - M);
            rs += (p0 + p1) + (p2 + p3);
            pb[nj] = pk4(p0, p1, p2, p3);
        }

        // ---- PV: O^T += V^T·P^T. Direct b64 V reads into K16 operands;
        // per-lane swizzle in the ADDRESS only; pb indices compile-time.
#pragma unroll
        for (int l = 0; l < 4; ++l) {
#pragma unroll
            for (int dj = 0; dj < 4; ++dj) {
                const unsigned short* vrow = &Vs[quad][(dj*16 + m16)*32 + ((l ^ fsw) * 8)];
                short4_t vlo = *(const short4_t*)vrow;
                short4_t vhi = *(const short4_t*)(vrow + 4);
                accO[dj] = MFMA_K16(vlo, pb[2*l],     accO[dj]);
                accO[dj] = MFMA_K16(vhi, pb[2*l + 1], accO[dj]);
            }
        }
    }

    // final l reduction (once)
    rs += __shfl_xor(rs, 16, 64);
    rs += __shfl_xor(rs, 32, 64);
    float rl = 1.0f / rs;
#pragma unroll
    for (int dj = 0; dj < 4; ++dj) {
        short4_t o = pk4(accO[dj][0]*rl, accO[dj][1]*rl,
                         accO[dj][2]*rl, accO[dj][3]*rl);
        *(short4_t*)&O[(size_t)(b*SEQ + qbase + m16)*D_EMBED
                       + h*HEAD_DIM + dj*16 + quad*4] = o;
    }
}

// ---------------------------------------------------------------------------
// y = LayerNorm(A + B)*g + be; A fp32, B bf16 -> fp32 Yf (and bf16 Yb if set)
// ---------------------------------------------------------------------------
__global__ __launch_bounds__(256) void ln_res(
    const float* __restrict__ A, const unsigned short* __restrict__ Bv,
    const float* __restrict__ g, const float* __restrict__ be,
    float* __restrict__ Yf, unsigned short* __restrict__ Yb)
{
    const int wave = threadIdx.x >> 6, lane = threadIdx.x & 63;
    const int row = blockIdx.x * 4 + wave;
    const float* ap = A + (size_t)row*512 + lane*8;
    short8 bv = *(const short8*)(Bv + (size_t)row*512 + lane*8);
    float v[8]; float s = 0.f;
#pragma unroll
    for (int j = 0; j < 8; j++) { v[j] = ap[j] + b2f(bv[j]); s += v[j]; }
#pragma unroll
    for (int off = 32; off >= 1; off >>= 1) s += __shfl_xor(s, off, 64);
    float mu = s * (1.f/512.f);
    float q = 0.f;
#pragma unroll
    for (int j = 0; j < 8; j++) { v[j] -= mu; q += v[j]*v[j]; }
#pragma unroll
    for (int off = 32; off >= 1; off >>= 1) q += __shfl_xor(q, off, 64);
    float rstd = rsqrtf(q * (1.f/512.f) + 1e-5f);
#pragma unroll
    for (int j = 0; j < 8; j++) {
        float y = v[j]*rstd*g[lane*8+j] + be[lane*8+j];
        if (Yf) Yf[(size_t)row*512 + lane*8 + j] = y;
        if (Yb) Yb[(size_t)row*512 + lane*8 + j] = f2b(y);
    }
}

__global__ __launch_bounds__(256) void cvt_f32_bf16(
    const float* __restrict__ X, unsigned short* __restrict__ Y, int n)
{
    int idx = (blockIdx.x * 256 + threadIdx.x) * 4;
    if (idx < n) {
        float4 v = *(const float4*)(X + idx);
        Y[idx+0] = f2b(v.x); Y[idx+1] = f2b(v.y);
        Y[idx+2] = f2b(v.z); Y[idx+3] = f2b(v.w);
    }
}

// W[K][N] fp32 -> WT[N][K] bf16. block (32,8), grid (N/32, K/32)
__global__ void transpose_w(const float* __restrict__ W, unsigned short* __restrict__ WT,
                            int K, int N)
{
    __shared__ float t[32][33];
    int n0 = blockIdx.x*32, k0 = blockIdx.y*32;
    int x = threadIdx.x, y = threadIdx.y;
#pragma unroll
    for (int yy = y; yy < 32; yy += 8) t[yy][x] = W[(size_t)(k0+yy)*N + n0 + x];
    __syncthreads();
#pragma unroll
    for (int yy = y; yy < 32; yy += 8) WT[(size_t)(n0+yy)*K + k0 + x] = f2b(t[x][yy]);
}

__global__ void concat3(const float* __restrict__ a, const float* __restrict__ b,
                        const float* __restrict__ c, float* __restrict__ o)
{
    int i = blockIdx.x*256 + threadIdx.x;  // 1536 total
    o[i] = (i < 512) ? a[i] : ((i < 1024) ? b[i-512] : c[i-1024]);
}

extern "C" void kernel_launch(void* const* d_in, const int* in_sizes, int n_in,
                              void* d_out, int out_size, void* d_ws, size_t ws_size,
                              hipStream_t stream)
{
    const float* x    = (const float*)d_in[0];
    const int*   mask = (const int*)  d_in[1];
    const float* Wq = (const float*)d_in[2];  const float* bq = (const float*)d_in[3];
    const float* Wk = (const float*)d_in[4];  const float* bk = (const float*)d_in[5];
    const float* Wv = (const float*)d_in[6];  const float* bv = (const float*)d_in[7];
    const float* Wo = (const float*)d_in[8];  const float* bo = (const float*)d_in[9];
    const float* ln1g = (const float*)d_in[10]; const float* ln1b = (const float*)d_in[11];
    const float* ln2g = (const float*)d_in[12]; const float* ln2b = (const float*)d_in[13];
    const float* W1 = (const float*)d_in[14]; const float* b1 = (const float*)d_in[15];
    const float* W2 = (const float*)d_in[16]; const float* b2 = (const float*)d_in[17];
    float* out = (float*)d_out;

    char* ws = (char*)d_ws;
    const size_t MB = 1024*1024;
    // liveness-planned map (peak 71 MB):
    unsigned short* xb    = (unsigned short*)(ws + 0);           // 0..8, dead after QKV GEMM
    unsigned short* WqkvT = (unsigned short*)(ws + 8*MB);        // 8..9.5
    unsigned short* W1T   = (unsigned short*)(ws + 10*MB);       // 10..12
    unsigned short* W2T   = (unsigned short*)(ws + 12*MB);       // 12..14
    unsigned short* WoT   = (unsigned short*)(ws + 14*MB);       // 14..14.5
    float*          bqkv  = (float*)(ws + 14*MB + 512*1024);     // 6 KB
    int*            mflag = (int*)(ws + 14*MB + 768*1024);       // 256 B
    unsigned*       kmaxb = (unsigned*)(ws + 14*MB + 772*1024);  // 64 B
    unsigned short* Qp    = (unsigned short*)(ws + 15*MB);       // 15..23, dead after flash
    unsigned short* Kp    = (unsigned short*)(ws + 23*MB);       // 23..31, dead after flash
    unsigned short* Vp    = (unsigned short*)(ws + 31*MB);       // 31..39, dead after flash
    unsigned short* ctx   = (unsigned short*)(ws + 39*MB);       // 39..47, dead after Wo GEMM
    unsigned short* atfb  = (unsigned short*)(ws + 47*MB);       // 47..55, dead after ln1
    float*          hf    = (float*)(ws + 55*MB);                // 55..71
    unsigned short* hb    = (unsigned short*)(ws + 0);           // 0..8, overlays dead xb
    unsigned short* Gb    = (unsigned short*)(ws + 15*MB);       // 15..47, overlays Qp/Kp/Vp/ctx
    unsigned short* ffb   = (unsigned short*)(ws + 47*MB);       // 47..55, overlays dead atfb

    dim3 tb(32, 8);
    cvt_f32_bf16<<<4096, 256, 0, stream>>>(x, xb, M_ROWS*D_EMBED);
    transpose_w<<<dim3(16,16), tb, 0, stream>>>(Wq, WqkvT,            512, 512);
    transpose_w<<<dim3(16,16), tb, 0, stream>>>(Wk, WqkvT + 512*512,  512, 512);
    transpose_w<<<dim3(16,16), tb, 0, stream>>>(Wv, WqkvT + 1024*512, 512, 512);
    transpose_w<<<dim3(16,16), tb, 0, stream>>>(Wo, WoT, 512, 512);
    transpose_w<<<dim3(64,16), tb, 0, stream>>>(W1, W1T, 512, 2048);
    transpose_w<<<dim3(16,64), tb, 0, stream>>>(W2, W2T, 2048, 512);
    concat3<<<6, 256, 0, stream>>>(bq, bk, bv, bqkv);
    mask_flags_k<<<1, 64, 0, stream>>>(mask, mflag);
    hipMemsetAsync(kmaxb, 0, 16*sizeof(unsigned), stream);

    // fused QKV projection -> direct Qp/Kp/Vp layouts (Q pre-scaled by QSCALE)
    gemm_qkv<<<dim3(12,64), 256, 0, stream>>>(xb, WqkvT, bqkv, Qp, Kp, Vp);

    kmax_k<<<dim3(16,16), 256, 0, stream>>>(Kp, kmaxb);
    flash_attn<<<dim3(SEQ/64, 16), 256, 0, stream>>>(Qp, Kp, Vp, mask, mflag, kmaxb, ctx);

    gemm_bt64<<<dim3(4,128), 256, 0, stream>>>(ctx, WoT, bo, atfb, M_ROWS, 512, 512);
    ln_res<<<M_ROWS/4, 256, 0, stream>>>(x, atfb, ln1g, ln1b, hf, hb);

    gemm_bt<2><<<dim3(16,64), 256, 0, stream>>>(hb, W1T, b1, Gb, M_ROWS, D_FF, 512);
    gemm_bt64<<<dim3(4,128), 256, 0, stream>>>(Gb, W2T, b2, ffb, M_ROWS, 512, D_FF);
    ln_res<<<M_ROWS/4, 256, 0, stream>>>(hf, ffb, ln2g, ln2b, out, (unsigned short*)nullptr);
}

// Round 11
// 381.190 us; speedup vs baseline: 2.3024x; 1.1225x over previous
//
#include <hip/hip_runtime.h>
#include <hip/hip_bf16.h>
#include <math.h>

#define D_EMBED 512
#define NUM_HEADS 8
#define HEAD_DIM 64
#define D_FF 2048
#define BATCH 2
#define SEQ 4096
#define M_ROWS (BATCH*SEQ)   // 8192
// 0.125 * log2(e): folds softmax's exp->exp2 conversion into the Q projection
#define QSCALE 0.18033688011112042f

typedef __attribute__((ext_vector_type(8))) short short8;
typedef __attribute__((ext_vector_type(4))) short short4_t;
typedef __attribute__((ext_vector_type(4))) float f32x4;

#if __has_builtin(__builtin_amdgcn_mfma_f32_16x16x16bf16_1k)
#define MFMA_K16(a,b,c) __builtin_amdgcn_mfma_f32_16x16x16bf16_1k(a,b,c,0,0,0)
#elif __has_builtin(__builtin_amdgcn_mfma_f32_16x16x16_bf16)
#define MFMA_K16(a,b,c) __builtin_amdgcn_mfma_f32_16x16x16_bf16(a,b,c,0,0,0)
#else
#define MFMA_K16(a,b,c) (c)   // host-pass parse stub
#endif

#if __has_builtin(__builtin_amdgcn_exp2f)
#define EXP2(x) __builtin_amdgcn_exp2f(x)
#else
#define EXP2(x) exp2f(x)
#endif

__device__ inline unsigned short f2b(float f) {
    union { float f; unsigned u; } v; v.f = f;
    unsigned r = v.u + 0x7fffu + ((v.u >> 16) & 1u);
    return (unsigned short)(r >> 16);
}

__device__ inline float b2f(short s) {
    union { unsigned u; float f; } v;
    v.u = ((unsigned)(unsigned short)s) << 16;
    return v.f;
}

// pack 4 fp32 -> 4 bf16 (RNE) via packed cvt
__device__ inline short4_t pk4(float p0, float p1, float p2, float p3) {
    union { __hip_bfloat162 h2[2]; short4_t s4; } u;
    u.h2[0] = __float22bfloat162_rn(make_float2(p0, p1));
    u.h2[1] = __float22bfloat162_rn(make_float2(p2, p3));
    return u.s4;
}

__device__ inline void gl2lds16(const void* g, void* l) {
    __builtin_amdgcn_global_load_lds(
        (const __attribute__((address_space(1))) unsigned int*)g,
        (__attribute__((address_space(3))) unsigned int*)l, 16, 0, 0);
}

// ---------------------------------------------------------------------------
// GEMM 128x128: C[M][N] = A[M][K](bf16) * BT[N][K](bf16)^T + bias
// EPI 0: bf16; EPI 2: GELU->bf16.
// ---------------------------------------------------------------------------
template<int EPI>
__global__ __launch_bounds__(256) void gemm_bt(
    const unsigned short* __restrict__ A, const unsigned short* __restrict__ BT,
    const float* __restrict__ bias, void* __restrict__ Cout,
    int M, int N, int K)
{
    __shared__ __align__(16) unsigned short As[128*32];
    __shared__ __align__(16) unsigned short Bs[128*32];
    const int tid  = threadIdx.x;
    const int wave = tid >> 6, lane = tid & 63;
    const int wy = wave >> 1, wx = wave & 1;
    const int quad = lane >> 4, m16 = lane & 15;
    const int row0 = blockIdx.y * 128, n0 = blockIdx.x * 128;
    const int rdoff = (quad ^ ((m16 >> 1) & 3)) * 8;   // swizzled read chunk

    f32x4 acc[4][4];
#pragma unroll
    for (int i = 0; i < 4; i++)
#pragma unroll
        for (int j = 0; j < 4; j++) acc[i][j] = (f32x4){0.f,0.f,0.f,0.f};

    const int kIters = K >> 5;
    for (int kt = 0; kt < kIters; ++kt) {
        const int k0 = kt << 5;
#pragma unroll
        for (int it = 0; it < 2; ++it) {
            int g  = it*256 + tid;
            int r  = g >> 2;
            int c8 = (((g & 3) ^ ((g >> 3) & 3)) << 3);   // swizzled source chunk
            gl2lds16(A  + (size_t)(row0 + r)*K + k0 + c8, &As[(size_t)(it*256 + wave*64)*8]);
            gl2lds16(BT + (size_t)(n0  + r)*K + k0 + c8, &Bs[(size_t)(it*256 + wave*64)*8]);
        }
        __syncthreads();
        short8 a[4], b[4];
#pragma unroll
        for (int i = 0; i < 4; i++) a[i] = *(const short8*)&As[(wy*64 + i*16 + m16)*32 + rdoff];
#pragma unroll
        for (int j = 0; j < 4; j++) b[j] = *(const short8*)&Bs[(wx*64 + j*16 + m16)*32 + rdoff];
#pragma unroll
        for (int i = 0; i < 4; i++)
#pragma unroll
            for (int j = 0; j < 4; j++)
                acc[i][j] = __builtin_amdgcn_mfma_f32_16x16x32_bf16(a[i], b[j], acc[i][j], 0, 0, 0);
        __syncthreads();
    }

#pragma unroll
    for (int j = 0; j < 4; j++) {
        int col = n0 + wx*64 + j*16 + m16;
        float bj = bias[col];
#pragma unroll
        for (int i = 0; i < 4; i++) {
            int rbase = row0 + wy*64 + i*16 + quad*4;
#pragma unroll
            for (int r = 0; r < 4; r++) {
                float v = acc[i][j][r] + bj;
                size_t idx = (size_t)(rbase + r)*N + col;
                if (EPI == 0) {
                    ((unsigned short*)Cout)[idx] = f2b(v);
                } else {
                    float gv = 0.5f * v * (1.0f + erff(v * 0.70710678118654752f));
                    ((unsigned short*)Cout)[idx] = f2b(gv);
                }
            }
        }
    }
}

// ---------------------------------------------------------------------------
// QKV GEMM: epilogue scatters directly into Qp/Kp/Vp layouts.
// Qp,Kp: [bh][SEQ][64]; Vp: [bh][kt][quad][64 d][32 key-frag].
// Q region pre-scaled by QSCALE. Region (Q/K/V) is uniform per block.
// ---------------------------------------------------------------------------
__global__ __launch_bounds__(256) void gemm_qkv(
    const unsigned short* __restrict__ A, const unsigned short* __restrict__ BT,
    const float* __restrict__ bias,
    unsigned short* __restrict__ Qp, unsigned short* __restrict__ Kp,
    unsigned short* __restrict__ Vp)
{
    const int K = 512;
    __shared__ __align__(16) unsigned short As[128*32];
    __shared__ __align__(16) unsigned short Bs[128*32];
    const int tid  = threadIdx.x;
    const int wave = tid >> 6, lane = tid & 63;
    const int wy = wave >> 1, wx = wave & 1;
    const int quad = lane >> 4, m16 = lane & 15;
    const int row0 = blockIdx.y * 128, n0 = blockIdx.x * 128;
    const int rdoff = (quad ^ ((m16 >> 1) & 3)) * 8;
    const int region = n0 >> 9;   // 0=Q, 1=K, 2=V (uniform per block)

    f32x4 acc[4][4];
#pragma unroll
    for (int i = 0; i < 4; i++)
#pragma unroll
        for (int j = 0; j < 4; j++) acc[i][j] = (f32x4){0.f,0.f,0.f,0.f};

    for (int kt = 0; kt < 16; ++kt) {
        const int k0 = kt << 5;
#pragma unroll
        for (int it = 0; it < 2; ++it) {
            int g  = it*256 + tid;
            int r  = g >> 2;
            int c8 = (((g & 3) ^ ((g >> 3) & 3)) << 3);
            gl2lds16(A  + (size_t)(row0 + r)*K + k0 + c8, &As[(size_t)(it*256 + wave*64)*8]);
            gl2lds16(BT + (size_t)(n0  + r)*K + k0 + c8, &Bs[(size_t)(it*256 + wave*64)*8]);
        }
        __syncthreads();
        short8 a[4], b[4];
#pragma unroll
        for (int i = 0; i < 4; i++) a[i] = *(const short8*)&As[(wy*64 + i*16 + m16)*32 + rdoff];
#pragma unroll
        for (int j = 0; j < 4; j++) b[j] = *(const short8*)&Bs[(wx*64 + j*16 + m16)*32 + rdoff];
#pragma unroll
        for (int i = 0; i < 4; i++)
#pragma unroll
            for (int j = 0; j < 4; j++)
                acc[i][j] = __builtin_amdgcn_mfma_f32_16x16x32_bf16(a[i], b[j], acc[i][j], 0, 0, 0);
        __syncthreads();
    }

    const float sc = (region == 0) ? QSCALE : 1.0f;
#pragma unroll
    for (int j = 0; j < 4; j++) {
        int col = n0 + wx*64 + j*16 + m16;
        float bj = bias[col];
        int cc = col & 511, h = cc >> 6, d = cc & 63;
#pragma unroll
        for (int i = 0; i < 4; i++) {
            int rbase = row0 + wy*64 + i*16 + quad*4;
#pragma unroll
            for (int r = 0; r < 4; r++) {
                float v = (acc[i][j][r] + bj) * sc;
                int row = rbase + r;
                int b = row >> 12, l = row & 4095;
                size_t bh = (size_t)(b*8 + h);
                if (region == 0) {
                    Qp[(bh*SEQ + l)*64 + d] = f2b(v);
                } else if (region == 1) {
                    Kp[(bh*SEQ + l)*64 + d] = f2b(v);
                } else {
                    int kt = l >> 7, kk = l & 127;
                    int qr = (kk >> 2) & 3, fi = (kk >> 4)*4 + (kk & 3);
                    Vp[((((bh*32 + kt)*4 + qr)*64 + d)*32) + fi] = f2b(v);
                }
            }
        }
    }
}

// ---------------------------------------------------------------------------
// GEMM 64x128 tile (N=512 matmuls: grid 512 blocks). bf16 out.
// ---------------------------------------------------------------------------
__global__ __launch_bounds__(256) void gemm_bt64(
    const unsigned short* __restrict__ A, const unsigned short* __restrict__ BT,
    const float* __restrict__ bias, unsigned short* __restrict__ Cout,
    int M, int N, int K)
{
    __shared__ __align__(16) unsigned short As[64*32];
    __shared__ __align__(16) unsigned short Bs[128*32];
    const int tid  = threadIdx.x;
    const int wave = tid >> 6, lane = tid & 63;
    const int wy = wave >> 1, wx = wave & 1;
    const int quad = lane >> 4, m16 = lane & 15;
    const int row0 = blockIdx.y * 64, n0 = blockIdx.x * 128;
    const int rdoff = (quad ^ ((m16 >> 1) & 3)) * 8;

    f32x4 acc[2][4];
#pragma unroll
    for (int i = 0; i < 2; i++)
#pragma unroll
        for (int j = 0; j < 4; j++) acc[i][j] = (f32x4){0.f,0.f,0.f,0.f};

    const int kIters = K >> 5;
    for (int kt = 0; kt < kIters; ++kt) {
        const int k0 = kt << 5;
        {
            int r = tid >> 2;
            int c8 = (((tid & 3) ^ ((tid >> 3) & 3)) << 3);
            gl2lds16(A + (size_t)(row0 + r)*K + k0 + c8, &As[(size_t)(wave*64)*8]);
        }
#pragma unroll
        for (int it = 0; it < 2; ++it) {
            int g  = it*256 + tid;
            int r  = g >> 2;
            int c8 = (((g & 3) ^ ((g >> 3) & 3)) << 3);
            gl2lds16(BT + (size_t)(n0 + r)*K + k0 + c8, &Bs[(size_t)(it*256 + wave*64)*8]);
        }
        __syncthreads();
        short8 a[2], b[4];
#pragma unroll
        for (int i = 0; i < 2; i++) a[i] = *(const short8*)&As[(wy*32 + i*16 + m16)*32 + rdoff];
#pragma unroll
        for (int j = 0; j < 4; j++) b[j] = *(const short8*)&Bs[(wx*64 + j*16 + m16)*32 + rdoff];
#pragma unroll
        for (int i = 0; i < 2; i++)
#pragma unroll
            for (int j = 0; j < 4; j++)
                acc[i][j] = __builtin_amdgcn_mfma_f32_16x16x32_bf16(a[i], b[j], acc[i][j], 0, 0, 0);
        __syncthreads();
    }

#pragma unroll
    for (int j = 0; j < 4; j++) {
        int col = n0 + wx*64 + j*16 + m16;
        float bj = bias[col];
#pragma unroll
        for (int i = 0; i < 2; i++) {
            int rbase = row0 + wy*32 + i*16 + quad*4;
#pragma unroll
            for (int r = 0; r < 4; r++) {
                float v = acc[i][j][r] + bj;
                Cout[(size_t)(rbase + r)*N + col] = f2b(v);
            }
        }
    }
}

// ---------------------------------------------------------------------------
// prep: all 6 weight transposes + bias concat + mask flags + kmax zero in ONE
// kernel. Blocks 0..3071 = 32x32 transpose tiles; block 3072 = misc.
// ---------------------------------------------------------------------------
__global__ __launch_bounds__(256) void prep(
    const float* __restrict__ Wq, const float* __restrict__ Wk,
    const float* __restrict__ Wv, const float* __restrict__ Wo,
    const float* __restrict__ W1, const float* __restrict__ W2,
    const float* __restrict__ bq, const float* __restrict__ bk,
    const float* __restrict__ bv, const int* __restrict__ mask,
    unsigned short* __restrict__ WqkvT, unsigned short* __restrict__ WoT,
    unsigned short* __restrict__ W1T, unsigned short* __restrict__ W2T,
    float* __restrict__ bqkv, int* __restrict__ mflag, unsigned* __restrict__ kmax2)
{
    const int id = blockIdx.x, t = threadIdx.x;
    if (id == 3072) {
        if (t < 64) {   // mask flags (64 key-tiles of 128)
            const int* m = mask + t*128;
            int all = 1;
            for (int i = 0; i < 128; i += 4) {
                int4 v = *(const int4*)(m + i);
                all &= (v.x && v.y && v.z && v.w) ? 1 : 0;
            }
            mflag[t] = all;
        }
        if (t < 16) kmax2[t] = 0u;
        for (int i = t; i < 1536; i += 256)
            bqkv[i] = (i < 512) ? bq[i] : ((i < 1024) ? bk[i-512] : bv[i-1024]);
        return;
    }
    __shared__ float tt[32][33];
    const float* W; unsigned short* WT; int K, N, bx, by;
    if (id < 256)       { W = Wq; WT = WqkvT;            K = 512;  N = 512;  bx = id & 15;  by = id >> 4; }
    else if (id < 512)  { int l = id - 256;  W = Wk; WT = WqkvT + 512*512;  K = 512;  N = 512;  bx = l & 15; by = l >> 4; }
    else if (id < 768)  { int l = id - 512;  W = Wv; WT = WqkvT + 1024*512; K = 512;  N = 512;  bx = l & 15; by = l >> 4; }
    else if (id < 1024) { int l = id - 768;  W = Wo; WT = WoT;              K = 512;  N = 512;  bx = l & 15; by = l >> 4; }
    else if (id < 2048) { int l = id - 1024; W = W1; WT = W1T;              K = 512;  N = 2048; bx = l & 63; by = l >> 6; }
    else                { int l = id - 2048; W = W2; WT = W2T;              K = 2048; N = 512;  bx = l & 15; by = l >> 4; }
    const int n0 = bx*32, k0 = by*32;
    const int x = t & 31, y = t >> 5;
#pragma unroll
    for (int yy = y; yy < 32; yy += 8) tt[yy][x] = W[(size_t)(k0+yy)*N + n0 + x];
    __syncthreads();
#pragma unroll
    for (int yy = y; yy < 32; yy += 8) WT[(size_t)(n0+yy)*K + k0 + x] = f2b(tt[x][yy]);
}

// kmax2[bh] = max_row ||K_row||^2, via atomicMax on positive-float bits.
__global__ __launch_bounds__(256) void kmax_k(
    const unsigned short* __restrict__ Kp, unsigned* __restrict__ kmax2)
{
    const int bh = blockIdx.x, t = threadIdx.x;
    const int row = blockIdx.y*256 + t;
    const unsigned short* kp = Kp + ((size_t)bh*SEQ + row)*64;
    float s = 0.f;
#pragma unroll
    for (int c = 0; c < 8; ++c) {
        short8 v = *(const short8*)(kp + c*8);
#pragma unroll
        for (int j = 0; j < 8; ++j) { float f = b2f(v[j]); s += f*f; }
    }
#pragma unroll
    for (int off = 32; off >= 1; off >>= 1)
        s = fmaxf(s, __shfl_xor(s, off, 64));
    if ((t & 63) == 0) atomicMax(&kmax2[bh], __float_as_uint(s));
}

// ---------------------------------------------------------------------------
// Flash attention, fixed-bound softmax. grid (SEQ/64, B*H), 256 threads.
// QK accumulator initialized with -M so MFMA emits (s - M) directly; mask
// overrides to -1e9 (exp2 -> 0). One l-reduction at the end.
// ---------------------------------------------------------------------------
__global__ __launch_bounds__(256) void flash_attn(
    const unsigned short* __restrict__ Qp, const unsigned short* __restrict__ Kp,
    const unsigned short* __restrict__ Vp, const int* __restrict__ mask,
    const int* __restrict__ flags, const unsigned* __restrict__ kmax2,
    unsigned short* __restrict__ O)
{
    __shared__ __align__(16) unsigned short Ks[2][128*32];
    __shared__ __align__(16) unsigned short Vs[4][64*32];
    const int tid = threadIdx.x, wave = tid >> 6, lane = tid & 63;
    const int quad = lane >> 4, m16 = lane & 15;
    const int bh = blockIdx.y, b = bh >> 3, h = bh & 7;
    const int qbase = blockIdx.x * 64 + wave * 16;
    const int fsw = (m16 >> 1) & 3;                  // row-derived swizzle key
    const int koff = (quad ^ fsw) * 8;               // Ks b128 read offset

    const unsigned short* Qb = Qp + (size_t)bh*SEQ*64;
    const unsigned short* Kb = Kp + (size_t)bh*SEQ*64;
    const unsigned short* Vb = Vp + (size_t)bh*32*4*64*32;
    const int* mbase = mask + b*SEQ;
    const int* fbase = flags + b*(SEQ/128);

    short8 qf[2];
    {
        const unsigned short* qp = Qb + (size_t)(qbase + m16)*64 + quad*8;
        qf[0] = *(const short8*)qp;
        qf[1] = *(const short8*)(qp + 32);
    }
    // fixed softmax bound M (per q row; includes QSCALE via q_hat)
    float qn2 = 0.f;
#pragma unroll
    for (int j = 0; j < 8; ++j) {
        float f0 = b2f(qf[0][j]), f1 = b2f(qf[1][j]);
        qn2 += f0*f0 + f1*f1;
    }
    qn2 += __shfl_xor(qn2, 16, 64);
    qn2 += __shfl_xor(qn2, 32, 64);
    const float M = sqrtf(qn2 * __uint_as_float(kmax2[bh]));
    const f32x4 cinit = (f32x4){-M, -M, -M, -M};

    f32x4 accO[4];
#pragma unroll
    for (int dj = 0; dj < 4; dj++) accO[dj] = (f32x4){0.f,0.f,0.f,0.f};
    float rs = 0.f;

    for (int kt = 0; kt < SEQ/128; ++kt) {
        const int key0 = kt * 128;
        const int allones = fbase[kt];
        __syncthreads();   // all waves done reading previous tile
        // stage K tile: two [128][32] halves, source-chunk swizzled
#pragma unroll
        for (int it = 0; it < 2; ++it) {
            int g = it*256 + tid;
            int r = g >> 2;
            int c8 = (((g & 3) ^ ((g >> 3) & 3)) << 3);
            gl2lds16(Kb + (size_t)(key0 + r)*64 + c8,      &Ks[0][(it*256 + wave*64)*8]);
            gl2lds16(Kb + (size_t)(key0 + r)*64 + 32 + c8, &Ks[1][(it*256 + wave*64)*8]);
        }
        // stage V tile: fragment-ordered Vp, per-row source-chunk swizzle
        {
            int d = wave*16 + (lane >> 2), ch = lane & 3;
            int c8 = (ch ^ ((d >> 1) & 3)) * 8;
#pragma unroll
            for (int qr = 0; qr < 4; ++qr)
                gl2lds16(Vb + (((size_t)kt*4 + qr)*64 + d)*32 + c8,
                         &Vs[qr][wave*64*8]);
        }
        __syncthreads();   // staging drained

        // ---- QK^T with C preloaded to -M -> p = 2^c directly
        short4_t pb[8];
#pragma unroll
        for (int nj = 0; nj < 8; ++nj) {
            short8 k0 = *(const short8*)&Ks[0][(nj*16 + m16)*32 + koff];
            short8 k1 = *(const short8*)&Ks[1][(nj*16 + m16)*32 + koff];
            f32x4 c = cinit;
            c = __builtin_amdgcn_mfma_f32_16x16x32_bf16(k0, qf[0], c, 0, 0, 0);
            c = __builtin_amdgcn_mfma_f32_16x16x32_bf16(k1, qf[1], c, 0, 0, 0);
            if (!allones) {
                int4 mv = *(const int4*)(mbase + key0 + nj*16 + quad*4);
                c[0] = mv.x ? c[0] : -1e9f;
                c[1] = mv.y ? c[1] : -1e9f;
                c[2] = mv.z ? c[2] : -1e9f;
                c[3] = mv.w ? c[3] : -1e9f;
            }
            float p0 = EXP2(c[0]);
            float p1 = EXP2(c[1]);
            float p2 = EXP2(c[2]);
            float p3 = EXP2(c[3]);
            rs += (p0 + p1) + (p2 + p3);
            pb[nj] = pk4(p0, p1, p2, p3);
        }

        // ---- PV: O^T += V^T·P^T. Direct b64 V reads into K16 operands;
        // per-lane swizzle in the ADDRESS only; pb indices compile-time.
#pragma unroll
        for (int l = 0; l < 4; ++l) {
#pragma unroll
            for (int dj = 0; dj < 4; ++dj) {
                const unsigned short* vrow = &Vs[quad][(dj*16 + m16)*32 + ((l ^ fsw) * 8)];
                short4_t vlo = *(const short4_t*)vrow;
                short4_t vhi = *(const short4_t*)(vrow + 4);
                accO[dj] = MFMA_K16(vlo, pb[2*l],     accO[dj]);
                accO[dj] = MFMA_K16(vhi, pb[2*l + 1], accO[dj]);
            }
        }
    }

    // final l reduction (once)
    rs += __shfl_xor(rs, 16, 64);
    rs += __shfl_xor(rs, 32, 64);
    float rl = 1.0f / rs;
#pragma unroll
    for (int dj = 0; dj < 4; ++dj) {
        short4_t o = pk4(accO[dj][0]*rl, accO[dj][1]*rl,
                         accO[dj][2]*rl, accO[dj][3]*rl);
        *(short4_t*)&O[(size_t)(b*SEQ + qbase + m16)*D_EMBED
                       + h*HEAD_DIM + dj*16 + quad*4] = o;
    }
}

// ---------------------------------------------------------------------------
// ln1: y = LayerNorm(x_f32 + attn_bf16)*g + be -> bf16 only
// ---------------------------------------------------------------------------
__global__ __launch_bounds__(256) void ln_res1(
    const float* __restrict__ A, const unsigned short* __restrict__ Bv,
    const float* __restrict__ g, const float* __restrict__ be,
    unsigned short* __restrict__ Yb)
{
    const int wave = threadIdx.x >> 6, lane = threadIdx.x & 63;
    const int row = blockIdx.x * 4 + wave;
    const float* ap = A + (size_t)row*512 + lane*8;
    short8 bv = *(const short8*)(Bv + (size_t)row*512 + lane*8);
    float v[8]; float s = 0.f;
#pragma unroll
    for (int j = 0; j < 8; j++) { v[j] = ap[j] + b2f(bv[j]); s += v[j]; }
#pragma unroll
    for (int off = 32; off >= 1; off >>= 1) s += __shfl_xor(s, off, 64);
    float mu = s * (1.f/512.f);
    float q = 0.f;
#pragma unroll
    for (int j = 0; j < 8; j++) { v[j] -= mu; q += v[j]*v[j]; }
#pragma unroll
    for (int off = 32; off >= 1; off >>= 1) q += __shfl_xor(q, off, 64);
    float rstd = rsqrtf(q * (1.f/512.f) + 1e-5f);
#pragma unroll
    for (int j = 0; j < 8; j++) {
        float y = v[j]*rstd*g[lane*8+j] + be[lane*8+j];
        Yb[(size_t)row*512 + lane*8 + j] = f2b(y);
    }
}

// ---------------------------------------------------------------------------
// ln2: y = LayerNorm(h_bf16 + ff_bf16)*g + be -> fp32 out
// ---------------------------------------------------------------------------
__global__ __launch_bounds__(256) void ln_res2(
    const unsigned short* __restrict__ A, const unsigned short* __restrict__ Bv,
    const float* __restrict__ g, const float* __restrict__ be,
    float* __restrict__ Yf)
{
    const int wave = threadIdx.x >> 6, lane = threadIdx.x & 63;
    const int row = blockIdx.x * 4 + wave;
    short8 av = *(const short8*)(A  + (size_t)row*512 + lane*8);
    short8 bv = *(const short8*)(Bv + (size_t)row*512 + lane*8);
    float v[8]; float s = 0.f;
#pragma unroll
    for (int j = 0; j < 8; j++) { v[j] = b2f(av[j]) + b2f(bv[j]); s += v[j]; }
#pragma unroll
    for (int off = 32; off >= 1; off >>= 1) s += __shfl_xor(s, off, 64);
    float mu = s * (1.f/512.f);
    float q = 0.f;
#pragma unroll
    for (int j = 0; j < 8; j++) { v[j] -= mu; q += v[j]*v[j]; }
#pragma unroll
    for (int off = 32; off >= 1; off >>= 1) q += __shfl_xor(q, off, 64);
    float rstd = rsqrtf(q * (1.f/512.f) + 1e-5f);
#pragma unroll
    for (int j = 0; j < 8; j++) {
        float y = v[j]*rstd*g[lane*8+j] + be[lane*8+j];
        Yf[(size_t)row*512 + lane*8 + j] = y;
    }
}

__global__ __launch_bounds__(256) void cvt_f32_bf16(
    const float* __restrict__ X, unsigned short* __restrict__ Y, int n)
{
    int idx = (blockIdx.x * 256 + threadIdx.x) * 4;
    if (idx < n) {
        float4 v = *(const float4*)(X + idx);
        Y[idx+0] = f2b(v.x); Y[idx+1] = f2b(v.y);
        Y[idx+2] = f2b(v.z); Y[idx+3] = f2b(v.w);
    }
}

extern "C" void kernel_launch(void* const* d_in, const int* in_sizes, int n_in,
                              void* d_out, int out_size, void* d_ws, size_t ws_size,
                              hipStream_t stream)
{
    const float* x    = (const float*)d_in[0];
    const int*   mask = (const int*)  d_in[1];
    const float* Wq = (const float*)d_in[2];  const float* bq = (const float*)d_in[3];
    const float* Wk = (const float*)d_in[4];  const float* bk = (const float*)d_in[5];
    const float* Wv = (const float*)d_in[6];  const float* bv = (const float*)d_in[7];
    const float* Wo = (const float*)d_in[8];  const float* bo = (const float*)d_in[9];
    const float* ln1g = (const float*)d_in[10]; const float* ln1b = (const float*)d_in[11];
    const float* ln2g = (const float*)d_in[12]; const float* ln2b = (const float*)d_in[13];
    const float* W1 = (const float*)d_in[14]; const float* b1 = (const float*)d_in[15];
    const float* W2 = (const float*)d_in[16]; const float* b2 = (const float*)d_in[17];
    float* out = (float*)d_out;

    char* ws = (char*)d_ws;
    const size_t MB = 1024*1024;
    // liveness-planned map (peak 55 MB):
    unsigned short* xb    = (unsigned short*)(ws + 0);           // 0..8, dead after QKV GEMM
    unsigned short* WqkvT = (unsigned short*)(ws + 8*MB);        // 8..9.5
    unsigned short* W1T   = (unsigned short*)(ws + 10*MB);       // 10..12
    unsigned short* W2T   = (unsigned short*)(ws + 12*MB);       // 12..14
    unsigned short* WoT   = (unsigned short*)(ws + 14*MB);       // 14..14.5
    float*          bqkv  = (float*)(ws + 14*MB + 512*1024);     // 6 KB
    int*            mflag = (int*)(ws + 14*MB + 768*1024);       // 256 B
    unsigned*       kmaxb = (unsigned*)(ws + 14*MB + 772*1024);  // 64 B
    unsigned short* Qp    = (unsigned short*)(ws + 15*MB);       // 15..23, dead after flash
    unsigned short* Kp    = (unsigned short*)(ws + 23*MB);       // 23..31, dead after flash
    unsigned short* Vp    = (unsigned short*)(ws + 31*MB);       // 31..39, dead after flash
    unsigned short* ctx   = (unsigned short*)(ws + 39*MB);       // 39..47, dead after Wo GEMM
    unsigned short* atfb  = (unsigned short*)(ws + 47*MB);       // 47..55, dead after ln1
    unsigned short* hb    = (unsigned short*)(ws + 0);           // 0..8, overlays dead xb
    unsigned short* Gb    = (unsigned short*)(ws + 15*MB);       // 15..47, overlays Qp/Kp/Vp/ctx
    unsigned short* ffb   = (unsigned short*)(ws + 47*MB);       // 47..55, overlays dead atfb

    cvt_f32_bf16<<<4096, 256, 0, stream>>>(x, xb, M_ROWS*D_EMBED);
    prep<<<3073, 256, 0, stream>>>(Wq, Wk, Wv, Wo, W1, W2, bq, bk, bv, mask,
                                   WqkvT, WoT, W1T, W2T, bqkv, mflag, kmaxb);

    // fused QKV projection -> direct Qp/Kp/Vp layouts (Q pre-scaled by QSCALE)
    gemm_qkv<<<dim3(12,64), 256, 0, stream>>>(xb, WqkvT, bqkv, Qp, Kp, Vp);

    kmax_k<<<dim3(16,16), 256, 0, stream>>>(Kp, kmaxb);
    flash_attn<<<dim3(SEQ/64, 16), 256, 0, stream>>>(Qp, Kp, Vp, mask, mflag, kmaxb, ctx);

    gemm_bt64<<<dim3(4,128), 256, 0, stream>>>(ctx, WoT, bo, atfb, M_ROWS, 512, 512);
    ln_res1<<<M_ROWS/4, 256, 0, stream>>>(x, atfb, ln1g, ln1b, hb);

    gemm_bt<2><<<dim3(16,64), 256, 0, stream>>>(hb, W1T, b1, Gb, M_ROWS, D_FF, 512);
    gemm_bt64<<<dim3(4,128), 256, 0, stream>>>(Gb, W2T, b2, ffb, M_ROWS, 512, D_FF);
    ln_res2<<<M_ROWS/4, 256, 0, stream>>>(hb, ffb, ln2g, ln2b, out);
}